// Round 17
// baseline (563.904 us; speedup 1.0000x reference)
//
#include <hip/hip_runtime.h>
#include <math.h>

#define BB 2
#define CCH 64
#define NN 4096
#define KK 9
#define TT 2
#define C2 128
#define C4 256
#define R1 (BB*NN)        /* 8192  */
#define RG (BB*NN*KK)     /* 73728 */
#define SPLIT 16
#define CHUNK (NN/SPLIT)  /* 256 */

#define WS_TOTAL 5194240ull
#define WS_BIG   (5194240ull + 9437184ull)   /* + Yg (RG*C2) */
#define WS_M1    (WS_BIG + 3448832ull)
#define WS_M2    (WS_M1 + 2752512ull)
#define WS_M3    (WS_M2 + 9641984ull)

typedef float f32x2 __attribute__((ext_vector_type(2)));
typedef float f32x4 __attribute__((ext_vector_type(4)));

__device__ __forceinline__ float gelu(float v){ return 0.5f*v*(1.f + erff(v*0.70710678118654752f)); }

__global__ void k_zero(float* __restrict__ o, int n){
  int i = blockIdx.x*256 + threadIdx.x;
  if (i < n) o[i] = 0.f;
}

// ---------------- transpose x (B,C,N) -> x0f (B,N,C) ----------------
__global__ void k_transpose(const float* __restrict__ x, float* __restrict__ x0f){
  int idx = blockIdx.x*256 + threadIdx.x;
  if (idx >= BB*NN*CCH) return;
  int c = idx & (CCH-1);
  int n = (idx >> 6) & (NN-1);
  int b = idx >> 18;
  x0f[idx] = x[(size_t)(b*CCH + c)*NN + n];
}

// ---------------- GEMM1 body (64->64) + stats ----------------
__device__ __forceinline__ void gemm1_body(int bx, int tid,
    const float* __restrict__ X, const float* __restrict__ W,
    const float* __restrict__ bias, float* __restrict__ Y,
    float* __restrict__ part, float* xT, float* s1, float* s2){
  int r0 = bx*32;
  #pragma unroll
  for (int u=0; u<2; u++){
    float4 v = ((const float4*)(X + (size_t)r0*64))[u*256+tid];
    int fi = (u*256+tid)*4;
    int r = fi >> 6, d = fi & 63;
    xT[(d+0)*34 + r] = v.x;
    xT[(d+1)*34 + r] = v.y;
    xT[(d+2)*34 + r] = v.z;
    xT[(d+3)*34 + r] = v.w;
  }
  __syncthreads();
  int tx = tid & 15, ty = tid >> 4;
  int c = tx*4, r = ty*2;
  float acc[2][4];
  #pragma unroll
  for (int i=0;i<2;i++){
    #pragma unroll
    for (int j=0;j<4;j++) acc[i][j] = 0.f;
  }
  for (int d=0; d<64; d++){
    float2 xv = *(const float2*)&xT[d*34 + r];
    float4 wv = *(const float4*)(W + d*64 + c);
    acc[0][0] = fmaf(xv.x, wv.x, acc[0][0]);
    acc[0][1] = fmaf(xv.x, wv.y, acc[0][1]);
    acc[0][2] = fmaf(xv.x, wv.z, acc[0][2]);
    acc[0][3] = fmaf(xv.x, wv.w, acc[0][3]);
    acc[1][0] = fmaf(xv.y, wv.x, acc[1][0]);
    acc[1][1] = fmaf(xv.y, wv.y, acc[1][1]);
    acc[1][2] = fmaf(xv.y, wv.z, acc[1][2]);
    acc[1][3] = fmaf(xv.y, wv.w, acc[1][3]);
  }
  float4 bz = *(const float4*)(bias + c);
  float bzv[4] = {bz.x, bz.y, bz.z, bz.w};
  float out0[4], out1[4];
  #pragma unroll
  for (int j=0;j<4;j++){
    out0[j] = acc[0][j] + bzv[j];
    out1[j] = acc[1][j] + bzv[j];
    s1[(c+j)*16+ty] = out0[j] + out1[j];
    s2[(c+j)*16+ty] = out0[j]*out0[j] + out1[j]*out1[j];
  }
  *(float4*)&Y[(size_t)(r0+r)*64 + c]   = make_float4(out0[0],out0[1],out0[2],out0[3]);
  *(float4*)&Y[(size_t)(r0+r+1)*64 + c] = make_float4(out1[0],out1[1],out1[2],out1[3]);
  __syncthreads();
  if (tid < 64){
    float sm=0.f, ss=0.f;
    #pragma unroll
    for (int q=0;q<16;q++){ sm += s1[tid*16+q]; ss += s2[tid*16+q]; }
    part[bx*128 + tid] = sm;
    part[bx*128 + 64 + tid] = ss;
  }
}

__global__ void k_gemm1_stats(const float* __restrict__ X, const float* __restrict__ W,
                              const float* __restrict__ bias, float* __restrict__ Y,
                              float* __restrict__ part){
  __shared__ float xT[64*34];
  __shared__ float s1[1024], s2[1024];
  gemm1_body(blockIdx.x, threadIdx.x, X, W, bias, Y, part, xT, s1, s2);
}

__global__ void k_gemm1M(const float* __restrict__ X, const float* __restrict__ W1b,
                         const float* __restrict__ b1b, float* __restrict__ Y0,
                         float* __restrict__ Y1, float* __restrict__ part0,
                         float* __restrict__ part1){
  __shared__ float xT[64*34];
  __shared__ float s1[1024], s2[1024];
  int t  = blockIdx.x >> 8;
  int bx = blockIdx.x & 255;
  gemm1_body(bx, threadIdx.x, X, W1b + t*CCH*CCH, b1b + t*64,
             t ? Y1 : Y0, t ? part1 : part0, xT, s1, s2);
}

// ---------------- GEMM2 body (128->64) + stats ----------------
__device__ __forceinline__ void gemm2_body(int bx, int tid,
    const float* __restrict__ X, const float* __restrict__ W,
    const float* __restrict__ bias, float* __restrict__ Y,
    float* __restrict__ part, float* xT, float* s1, float* s2){
  int r0 = bx*32;
  #pragma unroll
  for (int u=0; u<4; u++){
    float4 v = ((const float4*)(X + (size_t)r0*128))[u*256+tid];
    int fi = (u*256+tid)*4;
    int r = fi >> 7, d = fi & 127;
    xT[(d+0)*34 + r] = v.x;
    xT[(d+1)*34 + r] = v.y;
    xT[(d+2)*34 + r] = v.z;
    xT[(d+3)*34 + r] = v.w;
  }
  __syncthreads();
  int tx = tid & 15, ty = tid >> 4;
  int c = tx*4, r = ty*2;
  float acc[2][4];
  #pragma unroll
  for (int i=0;i<2;i++){
    #pragma unroll
    for (int j=0;j<4;j++) acc[i][j] = 0.f;
  }
  for (int d=0; d<128; d++){
    float2 xv = *(const float2*)&xT[d*34 + r];
    float4 wv = *(const float4*)(W + d*64 + c);
    acc[0][0] = fmaf(xv.x, wv.x, acc[0][0]);
    acc[0][1] = fmaf(xv.x, wv.y, acc[0][1]);
    acc[0][2] = fmaf(xv.x, wv.z, acc[0][2]);
    acc[0][3] = fmaf(xv.x, wv.w, acc[0][3]);
    acc[1][0] = fmaf(xv.y, wv.x, acc[1][0]);
    acc[1][1] = fmaf(xv.y, wv.y, acc[1][1]);
    acc[1][2] = fmaf(xv.y, wv.z, acc[1][2]);
    acc[1][3] = fmaf(xv.y, wv.w, acc[1][3]);
  }
  float4 bz = *(const float4*)(bias + c);
  float bzv[4] = {bz.x, bz.y, bz.z, bz.w};
  float out0[4], out1[4];
  #pragma unroll
  for (int j=0;j<4;j++){
    out0[j] = acc[0][j] + bzv[j];
    out1[j] = acc[1][j] + bzv[j];
    s1[(c+j)*16+ty] = out0[j] + out1[j];
    s2[(c+j)*16+ty] = out0[j]*out0[j] + out1[j]*out1[j];
  }
  *(float4*)&Y[(size_t)(r0+r)*64 + c]   = make_float4(out0[0],out0[1],out0[2],out0[3]);
  *(float4*)&Y[(size_t)(r0+r+1)*64 + c] = make_float4(out1[0],out1[1],out1[2],out1[3]);
  __syncthreads();
  if (tid < 64){
    float sm=0.f, ss=0.f;
    #pragma unroll
    for (int q=0;q<16;q++){ sm += s1[tid*16+q]; ss += s2[tid*16+q]; }
    part[bx*128 + tid] = sm;
    part[bx*128 + 64 + tid] = ss;
  }
}

__global__ void k_gemm2_stats(const float* __restrict__ X, const float* __restrict__ W,
                              const float* __restrict__ bias, float* __restrict__ Y,
                              float* __restrict__ part){
  __shared__ float xT[128*34];
  __shared__ float s1[1024], s2[1024];
  gemm2_body(blockIdx.x, threadIdx.x, X, W, bias, Y, part, xT, s1, s2);
}

__global__ void k_gemm2M(const float* __restrict__ X0, const float* __restrict__ X1,
                         const float* __restrict__ W2b, const float* __restrict__ b2b,
                         float* __restrict__ Y0, float* __restrict__ Y1,
                         float* __restrict__ part0, float* __restrict__ part1){
  __shared__ float xT[128*34];
  __shared__ float s1[1024], s2[1024];
  int t  = blockIdx.x >> 8;
  int bx = blockIdx.x & 255;
  gemm2_body(bx, threadIdx.x, t ? X1 : X0, W2b + t*C2*CCH, b2b + t*64,
             t ? Y1 : Y0, t ? part1 : part0, xT, s1, s2);
}

// ---------------- applynorm body ----------------
__device__ __forceinline__ void applynorm_body(int bx, int tid,
    float* __restrict__ h, const float* __restrict__ part,
    const float* __restrict__ g, const float* __restrict__ bt,
    float* __restrict__ xn, float* __restrict__ sq,
    float* scshL, float* s1, float* s2){
  {
    int c = tid & 63, sl = tid >> 6;
    float sm=0.f, ss=0.f;
    #pragma unroll 4
    for (int u=sl*64; u<sl*64+64; u++){ sm += part[u*128+c]; ss += part[u*128+64+c]; }
    s1[tid]=sm; s2[tid]=ss;
  }
  __syncthreads();
  if (tid < 64){
    float sm = s1[tid]+s1[64+tid]+s1[128+tid]+s1[192+tid];
    float ss = s2[tid]+s2[64+tid]+s2[128+tid]+s2[192+tid];
    float mean = sm/(float)R1;
    float var = fmaxf(ss/(float)R1 - mean*mean, 0.f);
    float sc = g[tid]*rsqrtf(var+1e-5f);
    scshL[tid] = sc; scshL[64+tid] = bt[tid] - mean*sc;
  }
  __syncthreads();
  int lane = tid & 63, w = tid >> 6;
  int r0 = bx*32;
  for (int it=0; it<8; it++){
    int r = r0 + w*8 + it;
    float v = fmaf(h[(size_t)r*64+lane], scshL[lane], scshL[64+lane]);
    h[(size_t)r*64+lane] = v;
    float s2v = v*v;
    #pragma unroll
    for (int off=32; off; off>>=1) s2v += __shfl_xor(s2v, off, 64);
    float den = fmaxf(sqrtf(s2v), 1e-12f);
    float xv = v/den;
    xn[(size_t)r*64+lane] = xv;
    float t2 = xv*xv;
    #pragma unroll
    for (int off=32; off; off>>=1) t2 += __shfl_xor(t2, off, 64);
    if (lane==0) sq[r] = t2;
  }
}

__global__ void k_applynorm3(float* __restrict__ h, const float* __restrict__ part,
                             const float* __restrict__ g, const float* __restrict__ bt,
                             float* __restrict__ xn, float* __restrict__ sq){
  __shared__ float scshL[128];
  __shared__ float s1[256], s2[256];
  applynorm_body(blockIdx.x, threadIdx.x, h, part, g, bt, xn, sq, scshL, s1, s2);
}

__global__ void k_applynormM(float* __restrict__ h0, float* __restrict__ h1,
                             const float* __restrict__ part0, const float* __restrict__ part1,
                             const float* __restrict__ g1b, const float* __restrict__ bt1b,
                             float* __restrict__ xn0, float* __restrict__ xn1,
                             float* __restrict__ sq0, float* __restrict__ sq1){
  __shared__ float scshL[128];
  __shared__ float s1[256], s2[256];
  int t  = blockIdx.x >> 8;
  int bx = blockIdx.x & 255;
  applynorm_body(bx, threadIdx.x, t ? h1 : h0, t ? part1 : part0,
                 g1b + t*64, bt1b + t*64, t ? xn1 : xn0, t ? sq1 : sq0,
                 scshL, s1, s2);
}

// ---------------- top-9 insert on packed u64 keys, branchless ----------------
__device__ __forceinline__ void topk_insert9u(unsigned long long key,
                                              unsigned long long* bk){
  bool c0 = key < bk[0], c1 = key < bk[1], c2 = key < bk[2], c3 = key < bk[3];
  bool c4 = key < bk[4], c5 = key < bk[5], c6 = key < bk[6], c7 = key < bk[7];
  bool c8 = key < bk[8];
  bk[8] = c7 ? bk[7] : (c8 ? key : bk[8]);
  bk[7] = c6 ? bk[6] : (c7 ? key : bk[7]);
  bk[6] = c5 ? bk[5] : (c6 ? key : bk[6]);
  bk[5] = c4 ? bk[4] : (c5 ? key : bk[5]);
  bk[4] = c3 ? bk[3] : (c4 ? key : bk[4]);
  bk[3] = c2 ? bk[2] : (c3 ? key : bk[3]);
  bk[2] = c1 ? bk[1] : (c2 ? key : bk[2]);
  bk[1] = c0 ? bk[0] : (c1 ? key : bk[1]);
  bk[0] = c0 ? key : bk[0];
}

// -------- KNN body (r8 config, floor ~120us/t) --------
__device__ __forceinline__ void knn_body(int bx, int tid,
                                         const float* __restrict__ xn,
                                         const float* __restrict__ sq,
                                         float* __restrict__ pd, int* __restrict__ pi_,
                                         float* xjL, float* sqL){
  int b     = bx >> 7;
  int ib    = (bx >> 4) & 7;
  int split = bx & 15;
  int half = tid >> 8;
  int li   = tid & 255;
  const float* xb = xn + (size_t)b*NN*64;
  const float* sqb = sq + (size_t)b*NN;
  int i0 = ib*512 + li;
  int i1 = i0 + 256;
  f32x4 xi0[16], xi1[16];
  {
    const f32x4* p0 = (const f32x4*)(xb + (size_t)i0*64);
    const f32x4* p1 = (const f32x4*)(xb + (size_t)i1*64);
    #pragma unroll
    for (int q=0;q<16;q++){ xi0[q] = p0[q]; xi1[q] = p1[q]; }
  }
  float sqi0 = sqb[i0], sqi1 = sqb[i1];
  unsigned long long bk0[9], bk1[9];
  #pragma unroll
  for (int q=0;q<9;q++){ bk0[q] = 0xFFFFFFFFFFFFFFFFull; bk1[q] = 0xFFFFFFFFFFFFFFFFull; }
  int jbase = split*CHUNK;
  {
    const float4* src = (const float4*)(xb + (size_t)jbase*64);
    float4* dst = (float4*)xjL;
    #pragma unroll
    for (int u=0; u<8; u++) dst[u*512 + tid] = src[u*512 + tid];
    if (tid < CHUNK) sqL[tid] = sq ? sqb[jbase + tid] : 0.f;
  }
  __syncthreads();
  int jl0 = half*128;
  #pragma unroll 1
  for (int jj=0; jj<128; jj++){
    int jl = jl0 + jj;
    const f32x4* xj4 = (const f32x4*)(xjL + jl*64);
    f32x2 a01_0 = {0.f, 0.f}, a23_0 = {0.f, 0.f};
    f32x2 a01_1 = {0.f, 0.f}, a23_1 = {0.f, 0.f};
    #pragma unroll
    for (int q=0;q<16;q++){
      f32x4 v = xj4[q];
      f32x2 vlo = __builtin_shufflevector(v, v, 0, 1);
      f32x2 vhi = __builtin_shufflevector(v, v, 2, 3);
      a01_0 = __builtin_elementwise_fma(__builtin_shufflevector(xi0[q], xi0[q], 0, 1), vlo, a01_0);
      a23_0 = __builtin_elementwise_fma(__builtin_shufflevector(xi0[q], xi0[q], 2, 3), vhi, a23_0);
      a01_1 = __builtin_elementwise_fma(__builtin_shufflevector(xi1[q], xi1[q], 0, 1), vlo, a01_1);
      a23_1 = __builtin_elementwise_fma(__builtin_shufflevector(xi1[q], xi1[q], 2, 3), vhi, a23_1);
    }
    float sqj = sqL[jl];
    int j = jbase + jl;
    float dot0 = (a01_0.x + a01_0.y) + (a23_0.x + a23_0.y);
    float dot1 = (a01_1.x + a01_1.y) + (a23_1.x + a23_1.y);
    float d0 = fmaxf(sqi0 + sqj - 2.f*dot0, 0.f);
    float d1 = fmaxf(sqi1 + sqj - 2.f*dot1, 0.f);
    unsigned long long key0 = ((unsigned long long)__float_as_uint(d0) << 32)
                            | (unsigned)j;
    unsigned long long key1 = ((unsigned long long)__float_as_uint(d1) << 32)
                            | (unsigned)j;
    topk_insert9u(key0, bk0);
    topk_insert9u(key1, bk1);
  }
  __syncthreads();
  unsigned long long* mL = (unsigned long long*)xjL;
  if (half == 1){
    #pragma unroll
    for (int q=0;q<9;q++){
      mL[(size_t)(li*2+0)*9+q] = bk0[q];
      mL[(size_t)(li*2+1)*9+q] = bk1[q];
    }
  }
  __syncthreads();
  if (half == 0){
    #pragma unroll
    for (int q=0;q<9;q++) topk_insert9u(mL[(size_t)(li*2+0)*9+q], bk0);
    #pragma unroll
    for (int q=0;q<9;q++) topk_insert9u(mL[(size_t)(li*2+1)*9+q], bk1);
    size_t base0 = (((size_t)(b*NN + i0))*SPLIT + split)*9;
    size_t base1 = (((size_t)(b*NN + i1))*SPLIT + split)*9;
    #pragma unroll
    for (int q=0;q<9;q++){
      pd[base0+q] = __uint_as_float((unsigned)(bk0[q] >> 32));
      pi_[base0+q] = (int)(unsigned)(bk0[q] & 0xFFFFFFFFull);
      pd[base1+q] = __uint_as_float((unsigned)(bk1[q] >> 32));
      pi_[base1+q] = (int)(unsigned)(bk1[q] & 0xFFFFFFFFull);
    }
  }
}

__global__ __launch_bounds__(512) __attribute__((amdgpu_waves_per_eu(2, 2)))
void k_knn(const float* __restrict__ xn,
           const float* __restrict__ sq,
           float* __restrict__ pd, int* __restrict__ pi_){
  __shared__ __align__(16) float xjL[CHUNK*64];   /* 64 KB */
  __shared__ float sqL[CHUNK];
  knn_body(blockIdx.x, threadIdx.x, xn, sq, pd, pi_, xjL, sqL);
}

// t-looped knn: one 256-block launch does t=0 then t=1 in-kernel, removing
// the inter-launch drain while keeping exactly 1 block/CU throughout
// (r14's 512-block merge staggered two block-waves and lost 8us).
__global__ __launch_bounds__(512) __attribute__((amdgpu_waves_per_eu(2, 2)))
void k_knn2(const float* __restrict__ xn0, const float* __restrict__ xn1,
            const float* __restrict__ sq0, const float* __restrict__ sq1,
            float* __restrict__ pd0, float* __restrict__ pd1,
            int* __restrict__ pi0, int* __restrict__ pi1){
  __shared__ __align__(16) float xjL[CHUNK*64];   /* 64 KB */
  __shared__ float sqL[CHUNK];
  knn_body(blockIdx.x, threadIdx.x, xn0, sq0, pd0, pi0, xjL, sqL);
  __syncthreads();   /* protect xjL merge-read vs next staging write */
  knn_body(blockIdx.x, threadIdx.x, xn1, sq1, pd1, pi1, xjL, sqL);
}

// ---------------- edge1 body: fused merge + edge-GEMM stats (+Yg store) ----------
__device__ __forceinline__ void edge1_body(int bx, int tid,
    const float* __restrict__ h, const float* __restrict__ pd,
    const int* __restrict__ pi_, const float* __restrict__ Wg,
    const float* __restrict__ bg, int* __restrict__ idxf,
    float* __restrict__ part, float* __restrict__ Yg, int storeYg,
    float* dxAll, float* xiAll, float* sSum, float* sSq){
  int lane = tid & 63, wv = tid >> 6;
  float* dxW = dxAll + wv*576;
  float* xiW = xiAll + wv*64;
  int c0 = lane, c1 = lane + 64;
  float bias0 = bg[c0], bias1 = bg[c1];
  float sm0=0.f, ss0=0.f, sm1=0.f, ss1=0.f;
  for (int u4=0; u4<4; u4++){
    int node = bx*16 + wv*4 + u4;
    int b = node >> 12;
    size_t cb = (size_t)node*(SPLIT*9);
    float d0 = pd[cb+lane], d1 = pd[cb+64+lane], d2 = INFINITY;
    int   j0 = pi_[cb+lane], j1 = pi_[cb+64+lane], j2 = 0x7fffffff;
    if (lane < 16){ d2 = pd[cb+128+lane]; j2 = pi_[cb+128+lane]; }
    int kidx[9];
    #pragma unroll
    for (int s=0; s<9; s++){
      float ld = d0; int lj = j0;
      if (d1 < ld || (d1 == ld && j1 < lj)){ ld = d1; lj = j1; }
      if (d2 < ld || (d2 == ld && j2 < lj)){ ld = d2; lj = j2; }
      #pragma unroll
      for (int off=1; off<64; off<<=1){
        float od = __shfl_xor(ld, off, 64);
        int   oj = __shfl_xor(lj, off, 64);
        if (od < ld || (od == ld && oj < lj)){ ld = od; lj = oj; }
      }
      kidx[s] = lj & (NN-1);
      if (lane == 0) idxf[(size_t)node*9 + s] = lj & (NN-1);
      if (j0 == lj){ d0 = INFINITY; j0 = 0x7fffffff; }
      if (j1 == lj){ d1 = INFINITY; j1 = 0x7fffffff; }
      if (j2 == lj){ d2 = INFINITY; j2 = 0x7fffffff; }
    }
    float xi_l = h[(size_t)node*64 + lane];
    xiW[lane] = xi_l;
    #pragma unroll
    for (int k=0; k<9; k++)
      dxW[k*64+lane] = h[((size_t)(b*NN + kidx[k]))*64 + lane] - xi_l;
    float common0 = bias0, common1 = bias1;
    const float4* xi4 = (const float4*)xiW;
    #pragma unroll 4
    for (int d4=0; d4<16; d4++){
      float4 xv = xi4[d4];
      int d = d4*4;
      common0 = fmaf(xv.x, Wg[(d+0)*C2+c0], common0);
      common0 = fmaf(xv.y, Wg[(d+1)*C2+c0], common0);
      common0 = fmaf(xv.z, Wg[(d+2)*C2+c0], common0);
      common0 = fmaf(xv.w, Wg[(d+3)*C2+c0], common0);
      common1 = fmaf(xv.x, Wg[(d+0)*C2+c1], common1);
      common1 = fmaf(xv.y, Wg[(d+1)*C2+c1], common1);
      common1 = fmaf(xv.z, Wg[(d+2)*C2+c1], common1);
      common1 = fmaf(xv.w, Wg[(d+3)*C2+c1], common1);
    }
    float a0[9], a1[9];
    #pragma unroll
    for (int k=0;k<9;k++){ a0[k]=0.f; a1[k]=0.f; }
    const float4* dx4 = (const float4*)dxW;
    for (int d4=0; d4<16; d4++){
      int d = d4*4;
      float w0v[4], w1v[4];
      #pragma unroll
      for (int i=0;i<4;i++){
        w0v[i] = Wg[(64+d+i)*C2+c0];
        w1v[i] = Wg[(64+d+i)*C2+c1];
      }
      #pragma unroll
      for (int k=0;k<9;k++){
        float4 dx = dx4[k*16+d4];
        a0[k] = fmaf(dx.x, w0v[0], a0[k]);
        a0[k] = fmaf(dx.y, w0v[1], a0[k]);
        a0[k] = fmaf(dx.z, w0v[2], a0[k]);
        a0[k] = fmaf(dx.w, w0v[3], a0[k]);
        a1[k] = fmaf(dx.x, w1v[0], a1[k]);
        a1[k] = fmaf(dx.y, w1v[1], a1[k]);
        a1[k] = fmaf(dx.z, w1v[2], a1[k]);
        a1[k] = fmaf(dx.w, w1v[3], a1[k]);
      }
    }
    #pragma unroll
    for (int k=0;k<9;k++){
      float v0 = common0 + a0[k], v1 = common1 + a1[k];
      sm0 += v0; ss0 += v0*v0; sm1 += v1; ss1 += v1*v1;
      if (storeYg){
        size_t yb = ((size_t)node*9 + k)*C2;
        Yg[yb + c0] = v0;
        Yg[yb + c1] = v1;
      }
    }
  }
  sSum[wv*128+lane] = sm0; sSum[wv*128+64+lane] = sm1;
  sSq [wv*128+lane] = ss0; sSq [wv*128+64+lane] = ss1;
  __syncthreads();
  if (tid < 128){
    float sm = sSum[tid]+sSum[128+tid]+sSum[256+tid]+sSum[384+tid];
    float ss = sSq[tid]+sSq[128+tid]+sSq[256+tid]+sSq[384+tid];
    part[bx*256 + tid] = sm;
    part[bx*256 + 128 + tid] = ss;
  }
}

__global__ __launch_bounds__(256) void k_edge1(const float* __restrict__ h,
                        const float* __restrict__ pd, const int* __restrict__ pi_,
                        const float* __restrict__ Wg, const float* __restrict__ bg,
                        int* __restrict__ idxf, float* __restrict__ part,
                        float* __restrict__ Yg, int storeYg){
  __shared__ float dxAll[4*576];
  __shared__ float xiAll[4*64];
  __shared__ float sSum[512], sSq[512];
  edge1_body(blockIdx.x, threadIdx.x, h, pd, pi_, Wg, bg, idxf, part, Yg, storeYg,
             dxAll, xiAll, sSum, sSq);
}

__global__ __launch_bounds__(256) void k_edge1M(
    const float* __restrict__ h0, const float* __restrict__ h1,
    const float* __restrict__ pd0, const float* __restrict__ pd1,
    const int* __restrict__ pi0, const int* __restrict__ pi1,
    const float* __restrict__ Wgb, const float* __restrict__ bgb,
    int* __restrict__ idxf0, int* __restrict__ idxf1,
    float* __restrict__ part0, float* __restrict__ part1,
    float* __restrict__ Yg0, float* __restrict__ Yg1){
  __shared__ float dxAll[4*576];
  __shared__ float xiAll[4*64];
  __shared__ float sSum[512], sSq[512];
  int t  = blockIdx.x >> 9;
  int bx = blockIdx.x & 511;
  edge1_body(bx, threadIdx.x, t ? h1 : h0, t ? pd1 : pd0, t ? pi1 : pi0,
             Wgb + t*C2*C2, bgb + t*C2, t ? idxf1 : idxf0,
             t ? part1 : part0, t ? Yg1 : Yg0, 1,
             dxAll, xiAll, sSum, sSq);
}

// ---------------- edge2m body: inline fin + BN + gelu + max over Yg ---------------
__device__ __forceinline__ void edge2m_body(int bx, int tid,
    const float* __restrict__ Yg, const float* __restrict__ part,
    const float* __restrict__ gg, const float* __restrict__ btg,
    float* __restrict__ gmax, float* scshL, float* s1, float* s2){
  {
    int cc = tid & 127, sl = tid >> 7;
    float sm=0.f, ss=0.f;
    #pragma unroll 4
    for (int u=sl*256; u<sl*256+256; u++){ sm += part[u*256+cc]; ss += part[u*256+128+cc]; }
    s1[tid]=sm; s2[tid]=ss;
  }
  __syncthreads();
  if (tid < 128){
    float sm = s1[tid]+s1[128+tid];
    float ss = s2[tid]+s2[128+tid];
    float mean = sm/(float)RG;
    float var = fmaxf(ss/(float)RG - mean*mean, 0.f);
    float sc = gg[tid]*rsqrtf(var+1e-5f);
    scshL[tid] = sc; scshL[128+tid] = btg[tid] - mean*sc;
  }
  __syncthreads();
  size_t base = (size_t)bx*2048;
  for (int p=0; p<8; p++){
    size_t idx = base + p*256 + tid;
    int c = idx & 127;
    size_t node = idx >> 7;
    float sc = scshL[c], sh = scshL[128+c];
    size_t yb = node*9*C2 + c;
    float m = -INFINITY;
    #pragma unroll
    for (int k=0;k<9;k++){
      m = fmaxf(m, gelu(fmaf(Yg[yb + (size_t)k*C2], sc, sh)));
    }
    gmax[idx] = m;
  }
}

__global__ __launch_bounds__(256) void k_edge2m(const float* __restrict__ Yg,
                        const float* __restrict__ part, const float* __restrict__ gg,
                        const float* __restrict__ btg, float* __restrict__ gmax){
  __shared__ float scshL[256];
  __shared__ float s1[256], s2[256];
  edge2m_body(blockIdx.x, threadIdx.x, Yg, part, gg, btg, gmax, scshL, s1, s2);
}

__global__ __launch_bounds__(256) void k_edge2mM(
    const float* __restrict__ Yg0, const float* __restrict__ Yg1,
    const float* __restrict__ part0, const float* __restrict__ part1,
    const float* __restrict__ ggb, const float* __restrict__ btgb,
    float* __restrict__ gmax0, float* __restrict__ gmax1){
  __shared__ float scshL[256];
  __shared__ float s1[256], s2[256];
  int t  = blockIdx.x >> 9;
  int bx = blockIdx.x & 511;
  edge2m_body(bx, threadIdx.x, t ? Yg1 : Yg0, t ? part1 : part0,
              ggb + t*C2, btgb + t*C2, t ? gmax1 : gmax0, scshL, s1, s2);
}

// ------- edge pass 2 (fallback): inline fin + recompute + BN + gelu + max ---------
__global__ __launch_bounds__(256) void k_edge2(const float* __restrict__ h,
                        const int* __restrict__ idxf,
                        const float* __restrict__ Wg, const float* __restrict__ bg,
                        const float* __restrict__ part, const float* __restrict__ gg,
                        const float* __restrict__ btg, float* __restrict__ gmax){
  __shared__ float dxAll[4*576];
  __shared__ float xiAll[4*64];
  __shared__ float scshL[256];
  __shared__ float s1[256], s2[256];
  int tid = threadIdx.x, lane = tid & 63, wv = tid >> 6;
  {
    int cc = tid & 127, sl = tid >> 7;
    float sm=0.f, ss=0.f;
    #pragma unroll 4
    for (int u=sl*256; u<sl*256+256; u++){ sm += part[u*256+cc]; ss += part[u*256+128+cc]; }
    s1[tid]=sm; s2[tid]=ss;
  }
  __syncthreads();
  if (tid < 128){
    float sm = s1[tid]+s1[128+tid];
    float ss = s2[tid]+s2[128+tid];
    float mean = sm/(float)RG;
    float var = fmaxf(ss/(float)RG - mean*mean, 0.f);
    float sc = gg[tid]*rsqrtf(var+1e-5f);
    scshL[tid] = sc; scshL[128+tid] = btg[tid] - mean*sc;
  }
  __syncthreads();
  float* dxW = dxAll + wv*576;
  float* xiW = xiAll + wv*64;
  int c0 = lane, c1 = lane + 64;
  float bias0 = bg[c0], bias1 = bg[c1];
  float sc0 = scshL[c0], sh0 = scshL[128+c0];
  float sc1 = scshL[c1], sh1 = scshL[128+c1];
  for (int u4=0; u4<4; u4++){
    int node = blockIdx.x*16 + wv*4 + u4;
    int b = node >> 12;
    int kidx[9];
    #pragma unroll
    for (int k=0;k<9;k++) kidx[k] = idxf[(size_t)node*9 + k] & (NN-1);
    float xi_l = h[(size_t)node*64 + lane];
    xiW[lane] = xi_l;
    #pragma unroll
    for (int k=0; k<9; k++)
      dxW[k*64+lane] = h[((size_t)(b*NN + kidx[k]))*64 + lane] - xi_l;
    float common0 = bias0, common1 = bias1;
    for (int d=0; d<64; d++){
      float xv = xiW[d];
      common0 = fmaf(xv, Wg[d*C2+c0], common0);
      common1 = fmaf(xv, Wg[d*C2+c1], common1);
    }
    float a0[9], a1[9];
    #pragma unroll
    for (int k=0;k<9;k++){ a0[k]=0.f; a1[k]=0.f; }
    for (int d=0; d<64; d++){
      float w0 = Wg[(64+d)*C2+c0], w1 = Wg[(64+d)*C2+c1];
      #pragma unroll
      for (int k=0;k<9;k++){
        float dxv = dxW[k*64+d];
        a0[k] = fmaf(dxv, w0, a0[k]);
        a1[k] = fmaf(dxv, w1, a1[k]);
      }
    }
    float m0 = -INFINITY, m1 = -INFINITY;
    #pragma unroll
    for (int k=0;k<9;k++){
      m0 = fmaxf(m0, gelu(fmaf(common0 + a0[k], sc0, sh0)));
      m1 = fmaxf(m1, gelu(fmaf(common1 + a1[k], sc1, sh1)));
    }
    gmax[(size_t)node*C2 + c0] = m0;
    gmax[(size_t)node*C2 + c1] = m1;
  }
}

// ---------------- FFN1 body ----------------
__device__ __forceinline__ void ffn1_body(int bx, int tid,
    const float* __restrict__ Y2, const float* __restrict__ part,
    const float* __restrict__ g2, const float* __restrict__ bt2,
    const float* __restrict__ x0f, float* __restrict__ outt,
    const float* __restrict__ Wf1, const float* __restrict__ bf1,
    float* __restrict__ partB, float* scshL, float* otT, float* s1, float* s2){
  int r0 = bx*32;
  {
    int c = tid & 63, sl = tid >> 6;
    float sm=0.f, ss=0.f;
    #pragma unroll 4
    for (int u=sl*64; u<sl*64+64; u++){ sm += part[u*128+c]; ss += part[u*128+64+c]; }
    s1[tid]=sm; s2[tid]=ss;
  }
  __syncthreads();
  if (tid < 64){
    float sm = s1[tid]+s1[64+tid]+s1[128+tid]+s1[192+tid];
    float ss = s2[tid]+s2[64+tid]+s2[128+tid]+s2[192+tid];
    float mean = sm/(float)R1;
    float var = fmaxf(ss/(float)R1 - mean*mean, 0.f);
    float sc = g2[tid]*rsqrtf(var+1e-5f);
    scshL[tid] = sc; scshL[64+tid] = bt2[tid] - mean*sc;
  }
  __syncthreads();
  #pragma unroll
  for (int p=0; p<8; p++){
    int idx = p*256 + tid;
    int lr = idx >> 6, cc = idx & 63;
    size_t gi = (size_t)(r0+lr)*64 + cc;
    float v = fmaf(Y2[gi], scshL[cc], scshL[64+cc]) + x0f[gi];
    otT[cc*36 + lr] = v;
    outt[gi] = v;
  }
  __syncthreads();
  int tx = tid & 63, ty = tid >> 6;
  int c = tx*4, r = ty*8;
  float acc[8][4];
  #pragma unroll
  for (int i=0;i<8;i++){
    #pragma unroll
    for (int j=0;j<4;j++) acc[i][j]=0.f;
  }
  for (int d=0; d<64; d++){
    float4 xa = *(const float4*)&otT[d*36 + r];
    float4 xb = *(const float4*)&otT[d*36 + r + 4];
    float4 wv = *(const float4*)(Wf1 + d*256 + c);
    float xs[8] = {xa.x,xa.y,xa.z,xa.w, xb.x,xb.y,xb.z,xb.w};
    #pragma unroll
    for (int i=0;i<8;i++){
      acc[i][0] = fmaf(xs[i], wv.x, acc[i][0]);
      acc[i][1] = fmaf(xs[i], wv.y, acc[i][1]);
      acc[i][2] = fmaf(xs[i], wv.z, acc[i][2]);
      acc[i][3] = fmaf(xs[i], wv.w, acc[i][3]);
    }
  }
  float4 bz = *(const float4*)(bf1 + c);
  float bzv[4] = {bz.x, bz.y, bz.z, bz.w};
  #pragma unroll
  for (int j=0;j<4;j++){
    float cs=0.f, cq=0.f;
    #pragma unroll
    for (int i=0;i<8;i++){
      float v = acc[i][j] + bzv[j];
      cs += v; cq += v*v;
    }
    s1[(c+j)*4 + ty] = cs;
    s2[(c+j)*4 + ty] = cq;
  }
  __syncthreads();
  {
    float sm = s1[tid*4]+s1[tid*4+1]+s1[tid*4+2]+s1[tid*4+3];
    float ss = s2[tid*4]+s2[tid*4+1]+s2[tid*4+2]+s2[tid*4+3];
    partB[bx*512 + tid] = sm;
    partB[bx*512 + 256 + tid] = ss;
  }
}

__global__ void k_ffn1_fused(const float* __restrict__ Y2, const float* __restrict__ part,
                             const float* __restrict__ g2, const float* __restrict__ bt2,
                             const float* __restrict__ x0f, float* __restrict__ outt,
                             const float* __restrict__ Wf1, const float* __restrict__ bf1,
                             float* __restrict__ partB){
  __shared__ float scshL[128];
  __shared__ float otT[64*36];
  __shared__ float s1[1024], s2[1024];
  ffn1_body(blockIdx.x, threadIdx.x, Y2, part, g2, bt2, x0f, outt, Wf1, bf1,
            partB, scshL, otT, s1, s2);
}

__global__ void k_ffn1M(const float* __restrict__ Y2_0, const float* __restrict__ Y2_1,
                        const float* __restrict__ part0, const float* __restrict__ part1,
                        const float* __restrict__ g2b, const float* __restrict__ bt2b,
                        const float* __restrict__ x0f,
                        float* __restrict__ outt0, float* __restrict__ outt1,
                        const float* __restrict__ Wf1b, const float* __restrict__ bf1b,
                        float* __restrict__ partB0, float* __restrict__ partB1){
  __shared__ float scshL[128];
  __shared__ float otT[64*36];
  __shared__ float s1[1024], s2[1024];
  int t  = blockIdx.x >> 8;
  int bx = blockIdx.x & 255;
  ffn1_body(bx, threadIdx.x, t ? Y2_1 : Y2_0, t ? part1 : part0,
            g2b + t*64, bt2b + t*64, x0f, t ? outt1 : outt0,
            Wf1b + t*CCH*C4, bf1b + t*C4, t ? partB1 : partB0,
            scshL, otT, s1, s2);
}

// ---------------- FFN2 body ----------------
__device__ __forceinline__ void ffn2_body(int bx, int tid,
    const float* __restrict__ outt, const float* __restrict__ Wf1,
    const float* __restrict__ bf1, const float* __restrict__ partB,
    const float* __restrict__ gf1, const float* __restrict__ btf1,
    const float* __restrict__ Wf2, const float* __restrict__ bf2,
    float* __restrict__ Yf2, float* __restrict__ partA,
    float* scshL, float* otT, float* fT, float* s1, float* s2){
  int r0 = bx*32;
  {
    float sm=0.f, ss=0.f;
    #pragma unroll 4
    for (int u=0; u<256; u++){ sm += partB[u*512+tid]; ss += partB[u*512+256+tid]; }
    float mean = sm/(float)R1;
    float var = fmaxf(ss/(float)R1 - mean*mean, 0.f);
    float sc = gf1[tid]*rsqrtf(var+1e-5f);
    scshL[tid] = sc; scshL[256+tid] = btf1[tid] - mean*sc;
  }
  #pragma unroll
  for (int p=0; p<8; p++){
    int idx = p*256 + tid;
    int lr = idx >> 6, cc = idx & 63;
    otT[cc*36 + lr] = outt[(size_t)r0*64 + idx];
  }
  __syncthreads();
  int tx = tid & 63, ty = tid >> 6;
  int c = tx*4, r = ty*8;
  {
    float acc[8][4];
    #pragma unroll
    for (int i=0;i<8;i++){
      #pragma unroll
      for (int j=0;j<4;j++) acc[i][j]=0.f;
    }
    for (int d=0; d<64; d++){
      float4 xa = *(const float4*)&otT[d*36 + r];
      float4 xb = *(const float4*)&otT[d*36 + r + 4];
      float4 wv = *(const float4*)(Wf1 + d*256 + c);
      float xs[8] = {xa.x,xa.y,xa.z,xa.w, xb.x,xb.y,xb.z,xb.w};
      #pragma unroll
      for (int i=0;i<8;i++){
        acc[i][0] = fmaf(xs[i], wv.x, acc[i][0]);
        acc[i][1] = fmaf(xs[i], wv.y, acc[i][1]);
        acc[i][2] = fmaf(xs[i], wv.z, acc[i][2]);
        acc[i][3] = fmaf(xs[i], wv.w, acc[i][3]);
      }
    }
    float4 bz = *(const float4*)(bf1 + c);
    float bzv[4] = {bz.x, bz.y, bz.z, bz.w};
    #pragma unroll
    for (int j=0;j<4;j++){
      float sc = scshL[c+j], sh = scshL[256+c+j];
      #pragma unroll
      for (int i=0;i<8;i++){
        float v = gelu(fmaf(acc[i][j] + bzv[j], sc, sh));
        fT[(c+j)*36 + r + i] = v;
      }
    }
  }
  __syncthreads();
  int tx2 = tid & 15, ty2 = tid >> 4;
  int c2 = tx2*4, r2 = ty2*2;
  float acc2[2][4];
  #pragma unroll
  for (int i=0;i<2;i++){
    #pragma unroll
    for (int j=0;j<4;j++) acc2[i][j]=0.f;
  }
  for (int d=0; d<256; d++){
    float2 xv = *(const float2*)&fT[d*36 + r2];
    float4 wv = *(const float4*)(Wf2 + d*64 + c2);
    acc2[0][0] = fmaf(xv.x, wv.x, acc2[0][0]);
    acc2[0][1] = fmaf(xv.x, wv.y, acc2[0][1]);
    acc2[0][2] = fmaf(xv.x, wv.z, acc2[0][2]);
    acc2[0][3] = fmaf(xv.x, wv.w, acc2[0][3]);
    acc2[1][0] = fmaf(xv.y, wv.x, acc2[1][0]);
    acc2[1][1] = fmaf(xv.y, wv.y, acc2[1][1]);
    acc2[1][2] = fmaf(xv.y, wv.z, acc2[1][2]);
    acc2[1][3] = fmaf(xv.y, wv.w, acc2[1][3]);
  }
  float4 b2 = *(const float4*)(bf2 + c2);
  float b2v[4] = {b2.x, b2.y, b2.z, b2.w};
  float out0[4], out1[4];
  #pragma unroll
  for (int j=0;j<4;j++){
    out0[j] = acc2[0][j] + b2v[j];
    out1[j] = acc2[1][j] + b2v[j];
    s1[(c2+j)*16 + ty2] = out0[j] + out1[j];
    s2[(c2+j)*16 + ty2] = out0[j]*out0[j] + out1[j]*out1[j];
  }
  *(float4*)&Yf2[(size_t)(r0+r2)*64 + c2]   = make_float4(out0[0],out0[1],out0[2],out0[3]);
  *(float4*)&Yf2[(size_t)(r0+r2+1)*64 + c2] = make_float4(out1[0],out1[1],out1[2],out1[3]);
  __syncthreads();
  if (tid < 64){
    float sm=0.f, ss=0.f;
    #pragma unroll
    for (int q=0;q<16;q++){ sm += s1[tid*16+q]; ss += s2[tid*16+q]; }
    partA[bx*128 + tid] = sm;
    partA[bx*128 + 64 + tid] = ss;
  }
}

__global__ void k_ffn2_fused(const float* __restrict__ outt, const float* __restrict__ Wf1,
                             const float* __restrict__ bf1, const float* __restrict__ partB,
                             const float* __restrict__ gf1, const float* __restrict__ btf1,
                             const float* __restrict__ Wf2, const float* __restrict__ bf2,
                             float* __restrict__ Yf2, float* __restrict__ partA){
  __shared__ float scshL[512];
  __shared__ float otT[64*36];
  __shared__ float fT[256*36];
  __shared__ float s1[1024], s2[1024];
  ffn2_body(blockIdx.x, threadIdx.x, outt, Wf1, bf1, partB, gf1, btf1, Wf2, bf2,
            Yf2, partA, scshL, otT, fT, s1, s2);
}

__global__ void k_ffn2M(const float* __restrict__ outt0, const float* __restrict__ outt1,
                        const float* __restrict__ Wf1b, const float* __restrict__ bf1b,
                        const float* __restrict__ partB0, const float* __restrict__ partB1,
                        const float* __restrict__ gf1b, const float* __restrict__ btf1b,
                        const float* __restrict__ Wf2b, const float* __restrict__ bf2b,
                        float* __restrict__ Yf2_0, float* __restrict__ Yf2_1,
                        float* __restrict__ partA0, float* __restrict__ partA1){
  __shared__ float scshL[512];
  __shared__ float otT[64*36];
  __shared__ float fT[256*36];
  __shared__ float s1[1024], s2[1024];
  int t  = blockIdx.x >> 8;
  int bx = blockIdx.x & 255;
  ffn2_body(bx, threadIdx.x, t ? outt1 : outt0, Wf1b + t*CCH*C4, bf1b + t*C4,
            t ? partB1 : partB0, gf1b + t*C4, btf1b + t*C4,
            Wf2b + t*C4*CCH, bf2b + t*64, t ? Yf2_1 : Yf2_0,
            t ? partA1 : partA0, scshL, otT, fT, s1, s2);
}

// ---------------- final body ----------------
__device__ __forceinline__ void final_body(int bx, int tid,
    const float* __restrict__ Yf2, const float* __restrict__ partA,
    const float* __restrict__ gf2, const float* __restrict__ btf2,
    const float* __restrict__ outt, float* __restrict__ feat,
    float* scshL, float* s1, float* s2){
  {
    int c = tid & 63, sl = tid >> 6;
    float sm=0.f, ss=0.f;
    #pragma unroll 4
    for (int u=sl*64; u<sl*64+64; u++){ sm += partA[u*128+c]; ss += partA[u*128+64+c]; }
    s1[tid]=sm; s2[tid]=ss;
  }
  __syncthreads();
  if (tid < 64){
    float sm = s1[tid]+s1[64+tid]+s1[128+tid]+s1[192+tid];
    float ss = s2[tid]+s2[64+tid]+s2[128+tid]+s2[192+tid];
    float mean = sm/(float)R1;
    float var = fmaxf(ss/(float)R1 - mean*mean, 0.f);
    float sc = gf2[tid]*rsqrtf(var+1e-5f);
    scshL[tid] = sc; scshL[64+tid] = btf2[tid] - mean*sc;
  }
  __syncthreads();
  size_t base = (size_t)bx*2048;
  for (int p=0; p<8; p++){
    size_t idx = base + p*256 + tid;
    int cc = idx & 63;
    feat[idx] = fmaf(Yf2[idx], scshL[cc], scshL[64+cc]) + outt[idx];
  }
}

__global__ void k_final(const float* __restrict__ Yf2, const float* __restrict__ partA,
                        const float* __restrict__ gf2, const float* __restrict__ btf2,
                        const float* __restrict__ outt, float* __restrict__ feat){
  __shared__ float scshL[128];
  __shared__ float s1[256], s2[256];
  final_body(blockIdx.x, threadIdx.x, Yf2, partA, gf2, btf2, outt, feat, scshL, s1, s2);
}

__global__ void k_finalM(const float* __restrict__ Yf2_0, const float* __restrict__ Yf2_1,
                         const float* __restrict__ partA0, const float* __restrict__ partA1,
                         const float* __restrict__ gf2b, const float* __restrict__ btf2b,
                         const float* __restrict__ outt0, const float* __restrict__ outt1,
                         float* __restrict__ f0, float* __restrict__ f1){
  __shared__ float scshL[128];
  __shared__ float s1[256], s2[256];
  int t  = blockIdx.x >> 8;
  int bx = blockIdx.x & 255;
  final_body(bx, threadIdx.x, t ? Yf2_1 : Yf2_0, t ? partA1 : partA0,
             gf2b + t*64, btf2b + t*64, t ? outt1 : outt0,
             t ? f1 : f0, scshL, s1, s2);
}

// ----- finalmix: BNf2+residual for BOTH t, alpha-mix, transposed write -> out -----
// Replaces finalM + k_mix in the merged3 path: skips the 8MB feat write + 4MB
// read and one launch. LDS 64c x 32n tile per t gives coalesced (c,n) writes.
__global__ void k_finalmix(const float* __restrict__ Yf2_0, const float* __restrict__ Yf2_1,
                           const float* __restrict__ partA0, const float* __restrict__ partA1,
                           const float* __restrict__ gf2b, const float* __restrict__ btf2b,
                           const float* __restrict__ outt0, const float* __restrict__ outt1,
                           const float* __restrict__ alpha, float* __restrict__ outv){
  __shared__ float scsh0[128], scsh1[128];
  __shared__ float s1[256], s2[256];
  __shared__ float tile0[64*33], tile1[64*33];
  int tid = threadIdx.x, bx = blockIdx.x;
  /* stats t=0 */
  {
    int c = tid & 63, sl = tid >> 6;
    float sm=0.f, ss=0.f;
    #pragma unroll 4
    for (int u=sl*64; u<sl*64+64; u++){ sm += partA0[u*128+c]; ss += partA0[u*128+64+c]; }
    s1[tid]=sm; s2[tid]=ss;
  }
  __syncthreads();
  if (tid < 64){
    float sm = s1[tid]+s1[64+tid]+s1[128+tid]+s1[192+tid];
    float ss = s2[tid]+s2[64+tid]+s2[128+tid]+s2[192+tid];
    float mean = sm/(float)R1;
    float var = fmaxf(ss/(float)R1 - mean*mean, 0.f);
    float sc = gf2b[tid]*rsqrtf(var+1e-5f);
    scsh0[tid] = sc; scsh0[64+tid] = btf2b[tid] - mean*sc;
  }
  __syncthreads();
  /* stats t=1 */
  {
    int c = tid & 63, sl = tid >> 6;
    float sm=0.f, ss=0.f;
    #pragma unroll 4
    for (int u=sl*64; u<sl*64+64; u++){ sm += partA1[u*128+c]; ss += partA1[u*128+64+c]; }
    s1[tid]=sm; s2[tid]=ss;
  }
  __syncthreads();
  if (tid < 64){
    float sm = s1[tid]+s1[64+tid]+s1[128+tid]+s1[192+tid];
    float ss = s2[tid]+s2[64+tid]+s2[128+tid]+s2[192+tid];
    float mean = sm/(float)R1;
    float var = fmaxf(ss/(float)R1 - mean*mean, 0.f);
    float sc = gf2b[64+tid]*rsqrtf(var+1e-5f);
    scsh1[tid] = sc; scsh1[64+tid] = btf2b[64+tid] - mean*sc;
  }
  __syncthreads();
  size_t base = (size_t)bx*2048;
  #pragma unroll
  for (int p=0; p<8; p++){
    size_t idx = base + p*256 + tid;
    int cc = idx & 63;
    int nl = (int)((idx >> 6) & 31);
    float f0v = fmaf(Yf2_0[idx], scsh0[cc], scsh0[64+cc]) + outt0[idx];
    float f1v = fmaf(Yf2_1[idx], scsh1[cc], scsh1[64+cc]) + outt1[idx];
    tile0[cc*33 + nl] = f0v;
    tile1[cc*33 + nl] = f1v;
  }
  __syncthreads();
  int b  = bx >> 7;            /* 128 blocks per b (4096/32) */
  int n0 = (bx & 127) * 32;
  float a00 = alpha[0], a01 = alpha[1];
  float a10 = alpha[TT], a11 = alpha[TT+1];
  #pragma unroll
  for (int q=0; q<2; q++){
    int slot = tid + q*256;      /* 0..511 */
    int c  = slot >> 3;          /* 0..63  */
    int f4 = slot & 7;           /* 0..7   */
    float v0[4], v1[4];
    #pragma unroll
    for (int k2=0;k2<4;k2++){
      v0[k2] = tile0[c*33 + f4*4 + k2];
      v1[k2] = tile1[c*33 + f4*4 + k2];
    }
    size_t o0 = ((size_t)((0*BB + b)*CCH + c))*NN + n0 + f4*4;
    size_t o1 = ((size_t)((1*BB + b)*CCH + c))*NN + n0 + f4*4;
    *(float4*)&outv[o0] = make_float4(a00*v0[0] + a01*v1[0], a00*v0[1] + a01*v1[1],
                                      a00*v0[2] + a01*v1[2], a00*v0[3] + a01*v1[3]);
    *(float4*)&outv[o1] = make_float4(a10*v0[0] + a11*v1[0], a10*v0[1] + a11*v1[1],
                                      a10*v0[2] + a11*v1[2], a10*v0[3] + a11*v1[3]);
  }
}

// ---------------- alpha-mix + transpose -> output (T,B,C,N) fp32 ----------------
__global__ void k_mix(const float* __restrict__ f0, const float* __restrict__ f1,
                      const float* __restrict__ alpha, float* __restrict__ outv){
  int idx = blockIdx.x*256 + threadIdx.x;
  if (idx >= TT*BB*CCH*NN) return;
  int n = idx & (NN-1);
  int c = (idx >> 12) & 63;
  int b = (idx >> 18) & 1;
  int i = idx >> 19;
  float a0 = alpha[i*TT + 0];
  float a1 = alpha[i*TT + 1];
  size_t fi = ((size_t)(b*NN + n))*64 + c;
  outv[idx] = a0*f0[fi] + a1*f1[fi];
}

extern "C" void kernel_launch(void* const* d_in, const int* in_sizes, int n_in,
                              void* d_out, int out_size, void* d_ws, size_t ws_size,
                              hipStream_t stream){
  float* outp = (float*)d_out;

  static const int expect[22] = {
    524288, 8192, 128, 128, 128, 32768, 256, 256, 256, 16384, 128, 128, 128,
    32768, 512, 512, 512, 32768, 128, 128, 128, 4
  };
  bool ok = (n_in == 22) && (out_size == TT*BB*CCH*NN) &&
            (ws_size >= WS_TOTAL*sizeof(float));
  if (ok){
    for (int i=0;i<22;i++) if (in_sizes[i] != expect[i]) { ok = false; break; }
  }
  if (!ok){
    k_zero<<<(out_size+255)/256,256,0,stream>>>(outp, out_size);
    return;
  }
  const bool bigws   = (ws_size >= WS_BIG*sizeof(float));
  const bool merged  = (ws_size >= WS_M1*sizeof(float));
  const bool merged2 = (ws_size >= WS_M2*sizeof(float));
  const bool merged3 = (ws_size >= WS_M3*sizeof(float));

  const float* x   = (const float*)d_in[0];
  const float* W1  = (const float*)d_in[1];
  const float* b1  = (const float*)d_in[2];
  const float* g1  = (const float*)d_in[3];
  const float* bt1 = (const float*)d_in[4];
  const float* Wg  = (const float*)d_in[5];
  const float* bg  = (const float*)d_in[6];
  const float* gg  = (const float*)d_in[7];
  const float* btg = (const float*)d_in[8];
  const float* W2  = (const float*)d_in[9];
  const float* b2v = (const float*)d_in[10];
  const float* g2  = (const float*)d_in[11];
  const float* bt2 = (const float*)d_in[12];
  const float* Wf1 = (const float*)d_in[13];
  const float* bf1v= (const float*)d_in[14];
  const float* gf1 = (const float*)d_in[15];
  const float* btf1= (const float*)d_in[16];
  const float* Wf2 = (const float*)d_in[17];
  const float* bf2v= (const float*)d_in[18];
  const float* gf2 = (const float*)d_in[19];
  const float* btf2= (const float*)d_in[20];
  const float* alpha=(const float*)d_in[21];
  float* ws = (float*)d_ws;

  float* x0f  = ws + 0;
  float* hbuf = ws + 524288;
  float* xnb  = ws + 1048576;
  float* sqb  = ws + 1572864;
  float* partA= ws + 1581056;
  int*   idxf = (int*)(ws + 1712640);
  float* f0   = ws + 1786368;
  float* f1b  = ws + 2310656;
  float* Rbig = ws + 2834944;
  float* pdist = Rbig;
  int*   pidx  = (int*)(Rbig + (size_t)R1*SPLIT*9);
  float* gmaxb = Rbig;
  float* outt  = Rbig + 1048576;
  float* Y2    = Rbig + 1572864;
  float* partB = Rbig + 2097152;
  float* Yf2   = Rbig;
  float* Yg    = ws + WS_TOTAL;
  /* merged-front tier buffers */
  float* hbuf1  = ws + WS_BIG;
  float* xnb1   = hbuf1 + 524288;
  float* sqb1   = xnb1 + 524288;
  float* partA1 = sqb1 + 8192;
  float* pd1    = partA1 + 32768;
  int*   pi1    = (int*)(pd1 + (size_t)R1*SPLIT*9);
  /* merged-back tier buffers */
  float* gmax1  = ws + WS_M1;
  float* Y2_1   = gmax1 + 1048576;
  float* outt1  = Y2_1 + 524288;
  float* partB1 = outt1 + 524288;
  float* Yf2_1  = partB1 + 131072;
  /* merged-edge tier buffers */
  float* Yg1    = ws + WS_M2;
  int*   idxf1  = (int*)(Yg1 + 9437184);
  float* partE1 = (float*)(idxf1 + 73728);

  k_transpose<<<2048,256,0,stream>>>(x, x0f);
  float* feats[2] = {f0, f1b};
  bool did_mix = false;

  if (merged){
    k_gemm1M<<<512,256,0,stream>>>(x0f, W1, b1, hbuf, hbuf1, partA, partA1);
    k_applynormM<<<512,256,0,stream>>>(hbuf, hbuf1, partA, partA1, g1, bt1,
                                       xnb, xnb1, sqb, sqb1);
    if (merged3){
      /* one knn launch, in-kernel t-loop (no inter-launch drain) */
      k_knn2<<<256,512,0,stream>>>(xnb, xnb1, sqb, sqb1, pdist, pd1, pidx, pi1);
      k_edge1M<<<1024,256,0,stream>>>(hbuf, hbuf1, pdist, pd1, pidx, pi1,
                                      Wg, bg, idxf, idxf1, partA, partE1,
                                      Yg, Yg1);
      k_edge2mM<<<1024,256,0,stream>>>(Yg, Yg1, partA, partE1, gg, btg,
                                       gmaxb, gmax1);
      k_gemm2M<<<512,256,0,stream>>>(gmaxb, gmax1, W2, b2v, Y2, Y2_1, partA, partA1);
      k_ffn1M<<<512,256,0,stream>>>(Y2, Y2_1, partA, partA1, g2, bt2, x0f,
                                    outt, outt1, Wf1, bf1v, partB, partB1);
      k_ffn2M<<<512,256,0,stream>>>(outt, outt1, Wf1, bf1v, partB, partB1,
                                    gf1, btf1, Wf2, bf2v, Yf2, Yf2_1, partA, partA1);
      k_finalmix<<<256,256,0,stream>>>(Yf2, Yf2_1, partA, partA1, gf2, btf2,
                                       outt, outt1, alpha, outp);
      did_mix = true;
    } else if (merged2){
      k_knn<<<256,512,0,stream>>>(xnb, sqb, pdist, pidx);
      k_knn<<<256,512,0,stream>>>(xnb1, sqb1, pd1, pi1);
      k_edge1<<<512,256,0,stream>>>(hbuf, pdist, pidx, Wg, bg, idxf, partA, Yg, 1);
      k_edge2m<<<512,256,0,stream>>>(Yg, partA, gg, btg, gmaxb);
      k_edge1<<<512,256,0,stream>>>(hbuf1, pd1, pi1, Wg + C2*C2, bg + C2, idxf, partA, Yg, 1);
      k_edge2m<<<512,256,0,stream>>>(Yg, partA, gg + C2, btg + C2, gmax1);
      k_gemm2M<<<512,256,0,stream>>>(gmaxb, gmax1, W2, b2v, Y2, Y2_1, partA, partA1);
      k_ffn1M<<<512,256,0,stream>>>(Y2, Y2_1, partA, partA1, g2, bt2, x0f,
                                    outt, outt1, Wf1, bf1v, partB, partB1);
      k_ffn2M<<<512,256,0,stream>>>(outt, outt1, Wf1, bf1v, partB, partB1,
                                    gf1, btf1, Wf2, bf2v, Yf2, Yf2_1, partA, partA1);
      k_finalM<<<512,256,0,stream>>>(Yf2, Yf2_1, partA, partA1, gf2, btf2,
                                     outt, outt1, f0, f1b);
    } else {
      k_knn<<<256,512,0,stream>>>(xnb, sqb, pdist, pidx);
      k_knn<<<256,512,0,stream>>>(xnb1, sqb1, pd1, pi1);
      for (int t=0; t<TT; t++){
        float* h_t  = t ? hbuf1 : hbuf;
        float* pd_t = t ? pd1 : pdist;
        int*   pi_t = t ? pi1 : pidx;
        k_edge1<<<512,256,0,stream>>>(h_t, pd_t, pi_t, Wg + t*C2*C2, bg + t*C2,
                                      idxf, partA, Yg, 1);
        k_edge2m<<<512,256,0,stream>>>(Yg, partA, gg + t*C2, btg + t*C2, gmaxb);
        k_gemm2_stats<<<256,256,0,stream>>>(gmaxb, W2 + t*C2*CCH, b2v + t*64, Y2, partA);
        k_ffn1_fused<<<256,256,0,stream>>>(Y2, partA, g2 + t*64, bt2 + t*64, x0f, outt,
                                           Wf1 + t*CCH*C4, bf1v + t*C4, partB);
        k_ffn2_fused<<<256,256,0,stream>>>(outt, Wf1 + t*CCH*C4, bf1v + t*C4, partB,
                                           gf1 + t*C4, btf1 + t*C4,
                                           Wf2 + t*C4*CCH, bf2v + t*64, Yf2, partA);
        k_final<<<256,256,0,stream>>>(Yf2, partA, gf2 + t*64, btf2 + t*64, outt, feats[t]);
      }
    }
  } else {
    for (int t=0; t<TT; t++){
      k_gemm1_stats<<<256,256,0,stream>>>(x0f, W1 + t*CCH*CCH, b1 + t*64, hbuf, partA);
      k_applynorm3<<<256,256,0,stream>>>(hbuf, partA, g1 + t*64, bt1 + t*64, xnb, sqb);
      k_knn<<<256,512,0,stream>>>(xnb, sqb, pdist, pidx);
      k_edge1<<<512,256,0,stream>>>(hbuf, pdist, pidx, Wg + t*C2*C2, bg + t*C2, idxf, partA,
                                    bigws ? Yg : hbuf, bigws ? 1 : 0);
      if (bigws){
        k_edge2m<<<512,256,0,stream>>>(Yg, partA, gg + t*C2, btg + t*C2, gmaxb);
      } else {
        k_edge2<<<512,256,0,stream>>>(hbuf, idxf, Wg + t*C2*C2, bg + t*C2,
                                      partA, gg + t*C2, btg + t*C2, gmaxb);
      }
      k_gemm2_stats<<<256,256,0,stream>>>(gmaxb, W2 + t*C2*CCH, b2v + t*64, Y2, partA);
      k_ffn1_fused<<<256,256,0,stream>>>(Y2, partA, g2 + t*64, bt2 + t*64, x0f, outt,
                                         Wf1 + t*CCH*C4, bf1v + t*C4, partB);
      k_ffn2_fused<<<256,256,0,stream>>>(outt, Wf1 + t*CCH*C4, bf1v + t*C4, partB,
                                         gf1 + t*C4, btf1 + t*C4,
                                         Wf2 + t*C4*CCH, bf2v + t*64, Yf2, partA);
      k_final<<<256,256,0,stream>>>(Yf2, partA, gf2 + t*64, btf2 + t*64, outt, feats[t]);
    }
  }
  if (!did_mix){
    k_mix<<<4096,256,0,stream>>>(f0, f1b, alpha, outp);
  }
}

// Round 19
// 537.035 us; speedup vs baseline: 1.0500x; 1.0500x over previous
//
#include <hip/hip_runtime.h>
#include <math.h>

#define BB 2
#define CCH 64
#define NN 4096
#define KK 9
#define TT 2
#define C2 128
#define C4 256
#define R1 (BB*NN)        /* 8192  */
#define RG (BB*NN*KK)     /* 73728 */
#define SPLIT 16
#define CHUNK (NN/SPLIT)  /* 256 */

#define WS_TOTAL 5194240ull
#define WS_BIG   (5194240ull + 9437184ull)   /* + Yg (RG*C2) */
#define WS_M1    (WS_BIG + 3448832ull)
#define WS_M2    (WS_M1 + 2752512ull)
#define WS_M3    (WS_M2 + 9641984ull)

typedef float f32x2 __attribute__((ext_vector_type(2)));
typedef float f32x4 __attribute__((ext_vector_type(4)));

__device__ __forceinline__ float gelu(float v){ return 0.5f*v*(1.f + erff(v*0.70710678118654752f)); }

__global__ void k_zero(float* __restrict__ o, int n){
  int i = blockIdx.x*256 + threadIdx.x;
  if (i < n) o[i] = 0.f;
}

// ---------------- transpose x (B,C,N) -> x0f (B,N,C) ----------------
__global__ void k_transpose(const float* __restrict__ x, float* __restrict__ x0f){
  int idx = blockIdx.x*256 + threadIdx.x;
  if (idx >= BB*NN*CCH) return;
  int c = idx & (CCH-1);
  int n = (idx >> 6) & (NN-1);
  int b = idx >> 18;
  x0f[idx] = x[(size_t)(b*CCH + c)*NN + n];
}

// ---------------- GEMM1 body (64->64) + stats ----------------
__device__ __forceinline__ void gemm1_body(int bx, int tid,
    const float* __restrict__ X, const float* __restrict__ W,
    const float* __restrict__ bias, float* __restrict__ Y,
    float* __restrict__ part, float* xT, float* s1, float* s2){
  int r0 = bx*32;
  #pragma unroll
  for (int u=0; u<2; u++){
    float4 v = ((const float4*)(X + (size_t)r0*64))[u*256+tid];
    int fi = (u*256+tid)*4;
    int r = fi >> 6, d = fi & 63;
    xT[(d+0)*34 + r] = v.x;
    xT[(d+1)*34 + r] = v.y;
    xT[(d+2)*34 + r] = v.z;
    xT[(d+3)*34 + r] = v.w;
  }
  __syncthreads();
  int tx = tid & 15, ty = tid >> 4;
  int c = tx*4, r = ty*2;
  float acc[2][4];
  #pragma unroll
  for (int i=0;i<2;i++){
    #pragma unroll
    for (int j=0;j<4;j++) acc[i][j] = 0.f;
  }
  for (int d=0; d<64; d++){
    float2 xv = *(const float2*)&xT[d*34 + r];
    float4 wv = *(const float4*)(W + d*64 + c);
    acc[0][0] = fmaf(xv.x, wv.x, acc[0][0]);
    acc[0][1] = fmaf(xv.x, wv.y, acc[0][1]);
    acc[0][2] = fmaf(xv.x, wv.z, acc[0][2]);
    acc[0][3] = fmaf(xv.x, wv.w, acc[0][3]);
    acc[1][0] = fmaf(xv.y, wv.x, acc[1][0]);
    acc[1][1] = fmaf(xv.y, wv.y, acc[1][1]);
    acc[1][2] = fmaf(xv.y, wv.z, acc[1][2]);
    acc[1][3] = fmaf(xv.y, wv.w, acc[1][3]);
  }
  float4 bz = *(const float4*)(bias + c);
  float bzv[4] = {bz.x, bz.y, bz.z, bz.w};
  float out0[4], out1[4];
  #pragma unroll
  for (int j=0;j<4;j++){
    out0[j] = acc[0][j] + bzv[j];
    out1[j] = acc[1][j] + bzv[j];
    s1[(c+j)*16+ty] = out0[j] + out1[j];
    s2[(c+j)*16+ty] = out0[j]*out0[j] + out1[j]*out1[j];
  }
  *(float4*)&Y[(size_t)(r0+r)*64 + c]   = make_float4(out0[0],out0[1],out0[2],out0[3]);
  *(float4*)&Y[(size_t)(r0+r+1)*64 + c] = make_float4(out1[0],out1[1],out1[2],out1[3]);
  __syncthreads();
  if (tid < 64){
    float sm=0.f, ss=0.f;
    #pragma unroll
    for (int q=0;q<16;q++){ sm += s1[tid*16+q]; ss += s2[tid*16+q]; }
    part[bx*128 + tid] = sm;
    part[bx*128 + 64 + tid] = ss;
  }
}

__global__ void k_gemm1_stats(const float* __restrict__ X, const float* __restrict__ W,
                              const float* __restrict__ bias, float* __restrict__ Y,
                              float* __restrict__ part){
  __shared__ float xT[64*34];
  __shared__ float s1[1024], s2[1024];
  gemm1_body(blockIdx.x, threadIdx.x, X, W, bias, Y, part, xT, s1, s2);
}

__global__ void k_gemm1M(const float* __restrict__ X, const float* __restrict__ W1b,
                         const float* __restrict__ b1b, float* __restrict__ Y0,
                         float* __restrict__ Y1, float* __restrict__ part0,
                         float* __restrict__ part1){
  __shared__ float xT[64*34];
  __shared__ float s1[1024], s2[1024];
  int t  = blockIdx.x >> 8;
  int bx = blockIdx.x & 255;
  gemm1_body(bx, threadIdx.x, X, W1b + t*CCH*CCH, b1b + t*64,
             t ? Y1 : Y0, t ? part1 : part0, xT, s1, s2);
}

// ---------------- GEMM2 body (128->64) + stats ----------------
__device__ __forceinline__ void gemm2_body(int bx, int tid,
    const float* __restrict__ X, const float* __restrict__ W,
    const float* __restrict__ bias, float* __restrict__ Y,
    float* __restrict__ part, float* xT, float* s1, float* s2){
  int r0 = bx*32;
  #pragma unroll
  for (int u=0; u<4; u++){
    float4 v = ((const float4*)(X + (size_t)r0*128))[u*256+tid];
    int fi = (u*256+tid)*4;
    int r = fi >> 7, d = fi & 127;
    xT[(d+0)*34 + r] = v.x;
    xT[(d+1)*34 + r] = v.y;
    xT[(d+2)*34 + r] = v.z;
    xT[(d+3)*34 + r] = v.w;
  }
  __syncthreads();
  int tx = tid & 15, ty = tid >> 4;
  int c = tx*4, r = ty*2;
  float acc[2][4];
  #pragma unroll
  for (int i=0;i<2;i++){
    #pragma unroll
    for (int j=0;j<4;j++) acc[i][j] = 0.f;
  }
  for (int d=0; d<128; d++){
    float2 xv = *(const float2*)&xT[d*34 + r];
    float4 wv = *(const float4*)(W + d*64 + c);
    acc[0][0] = fmaf(xv.x, wv.x, acc[0][0]);
    acc[0][1] = fmaf(xv.x, wv.y, acc[0][1]);
    acc[0][2] = fmaf(xv.x, wv.z, acc[0][2]);
    acc[0][3] = fmaf(xv.x, wv.w, acc[0][3]);
    acc[1][0] = fmaf(xv.y, wv.x, acc[1][0]);
    acc[1][1] = fmaf(xv.y, wv.y, acc[1][1]);
    acc[1][2] = fmaf(xv.y, wv.z, acc[1][2]);
    acc[1][3] = fmaf(xv.y, wv.w, acc[1][3]);
  }
  float4 bz = *(const float4*)(bias + c);
  float bzv[4] = {bz.x, bz.y, bz.z, bz.w};
  float out0[4], out1[4];
  #pragma unroll
  for (int j=0;j<4;j++){
    out0[j] = acc[0][j] + bzv[j];
    out1[j] = acc[1][j] + bzv[j];
    s1[(c+j)*16+ty] = out0[j] + out1[j];
    s2[(c+j)*16+ty] = out0[j]*out0[j] + out1[j]*out1[j];
  }
  *(float4*)&Y[(size_t)(r0+r)*64 + c]   = make_float4(out0[0],out0[1],out0[2],out0[3]);
  *(float4*)&Y[(size_t)(r0+r+1)*64 + c] = make_float4(out1[0],out1[1],out1[2],out1[3]);
  __syncthreads();
  if (tid < 64){
    float sm=0.f, ss=0.f;
    #pragma unroll
    for (int q=0;q<16;q++){ sm += s1[tid*16+q]; ss += s2[tid*16+q]; }
    part[bx*128 + tid] = sm;
    part[bx*128 + 64 + tid] = ss;
  }
}

__global__ void k_gemm2_stats(const float* __restrict__ X, const float* __restrict__ W,
                              const float* __restrict__ bias, float* __restrict__ Y,
                              float* __restrict__ part){
  __shared__ float xT[128*34];
  __shared__ float s1[1024], s2[1024];
  gemm2_body(blockIdx.x, threadIdx.x, X, W, bias, Y, part, xT, s1, s2);
}

__global__ void k_gemm2M(const float* __restrict__ X0, const float* __restrict__ X1,
                         const float* __restrict__ W2b, const float* __restrict__ b2b,
                         float* __restrict__ Y0, float* __restrict__ Y1,
                         float* __restrict__ part0, float* __restrict__ part1){
  __shared__ float xT[128*34];
  __shared__ float s1[1024], s2[1024];
  int t  = blockIdx.x >> 8;
  int bx = blockIdx.x & 255;
  gemm2_body(bx, threadIdx.x, t ? X1 : X0, W2b + t*C2*CCH, b2b + t*64,
             t ? Y1 : Y0, t ? part1 : part0, xT, s1, s2);
}

// ---------------- applynorm body ----------------
__device__ __forceinline__ void applynorm_body(int bx, int tid,
    float* __restrict__ h, const float* __restrict__ part,
    const float* __restrict__ g, const float* __restrict__ bt,
    float* __restrict__ xn, float* __restrict__ sq,
    float* scshL, float* s1, float* s2){
  {
    int c = tid & 63, sl = tid >> 6;
    float sm=0.f, ss=0.f;
    #pragma unroll 4
    for (int u=sl*64; u<sl*64+64; u++){ sm += part[u*128+c]; ss += part[u*128+64+c]; }
    s1[tid]=sm; s2[tid]=ss;
  }
  __syncthreads();
  if (tid < 64){
    float sm = s1[tid]+s1[64+tid]+s1[128+tid]+s1[192+tid];
    float ss = s2[tid]+s2[64+tid]+s2[128+tid]+s2[192+tid];
    float mean = sm/(float)R1;
    float var = fmaxf(ss/(float)R1 - mean*mean, 0.f);
    float sc = g[tid]*rsqrtf(var+1e-5f);
    scshL[tid] = sc; scshL[64+tid] = bt[tid] - mean*sc;
  }
  __syncthreads();
  int lane = tid & 63, w = tid >> 6;
  int r0 = bx*32;
  for (int it=0; it<8; it++){
    int r = r0 + w*8 + it;
    float v = fmaf(h[(size_t)r*64+lane], scshL[lane], scshL[64+lane]);
    h[(size_t)r*64+lane] = v;
    float s2v = v*v;
    #pragma unroll
    for (int off=32; off; off>>=1) s2v += __shfl_xor(s2v, off, 64);
    float den = fmaxf(sqrtf(s2v), 1e-12f);
    float xv = v/den;
    xn[(size_t)r*64+lane] = xv;
    float t2 = xv*xv;
    #pragma unroll
    for (int off=32; off; off>>=1) t2 += __shfl_xor(t2, off, 64);
    if (lane==0) sq[r] = t2;
  }
}

__global__ void k_applynorm3(float* __restrict__ h, const float* __restrict__ part,
                             const float* __restrict__ g, const float* __restrict__ bt,
                             float* __restrict__ xn, float* __restrict__ sq){
  __shared__ float scshL[128];
  __shared__ float s1[256], s2[256];
  applynorm_body(blockIdx.x, threadIdx.x, h, part, g, bt, xn, sq, scshL, s1, s2);
}

__global__ void k_applynormM(float* __restrict__ h0, float* __restrict__ h1,
                             const float* __restrict__ part0, const float* __restrict__ part1,
                             const float* __restrict__ g1b, const float* __restrict__ bt1b,
                             float* __restrict__ xn0, float* __restrict__ xn1,
                             float* __restrict__ sq0, float* __restrict__ sq1){
  __shared__ float scshL[128];
  __shared__ float s1[256], s2[256];
  int t  = blockIdx.x >> 8;
  int bx = blockIdx.x & 255;
  applynorm_body(bx, threadIdx.x, t ? h1 : h0, t ? part1 : part0,
                 g1b + t*64, bt1b + t*64, t ? xn1 : xn0, t ? sq1 : sq0,
                 scshL, s1, s2);
}

// ---------------- top-9 insert on packed u64 keys, branchless ----------------
__device__ __forceinline__ void topk_insert9u(unsigned long long key,
                                              unsigned long long* bk){
  bool c0 = key < bk[0], c1 = key < bk[1], c2 = key < bk[2], c3 = key < bk[3];
  bool c4 = key < bk[4], c5 = key < bk[5], c6 = key < bk[6], c7 = key < bk[7];
  bool c8 = key < bk[8];
  bk[8] = c7 ? bk[7] : (c8 ? key : bk[8]);
  bk[7] = c6 ? bk[6] : (c7 ? key : bk[7]);
  bk[6] = c5 ? bk[5] : (c6 ? key : bk[6]);
  bk[5] = c4 ? bk[4] : (c5 ? key : bk[5]);
  bk[4] = c3 ? bk[3] : (c4 ? key : bk[4]);
  bk[3] = c2 ? bk[2] : (c3 ? key : bk[3]);
  bk[2] = c1 ? bk[1] : (c2 ? key : bk[2]);
  bk[1] = c0 ? bk[0] : (c1 ? key : bk[1]);
  bk[0] = c0 ? key : bk[0];
}

// -------- KNN body (r8 config, floor ~120us/t) --------
__device__ __forceinline__ void knn_body(int bx, int tid,
                                         const float* __restrict__ xn,
                                         const float* __restrict__ sq,
                                         float* __restrict__ pd, int* __restrict__ pi_,
                                         float* xjL, float* sqL){
  int b     = bx >> 7;
  int ib    = (bx >> 4) & 7;
  int split = bx & 15;
  int half = tid >> 8;
  int li   = tid & 255;
  const float* xb = xn + (size_t)b*NN*64;
  const float* sqb = sq + (size_t)b*NN;
  int i0 = ib*512 + li;
  int i1 = i0 + 256;
  f32x4 xi0[16], xi1[16];
  {
    const f32x4* p0 = (const f32x4*)(xb + (size_t)i0*64);
    const f32x4* p1 = (const f32x4*)(xb + (size_t)i1*64);
    #pragma unroll
    for (int q=0;q<16;q++){ xi0[q] = p0[q]; xi1[q] = p1[q]; }
  }
  float sqi0 = sqb[i0], sqi1 = sqb[i1];
  unsigned long long bk0[9], bk1[9];
  #pragma unroll
  for (int q=0;q<9;q++){ bk0[q] = 0xFFFFFFFFFFFFFFFFull; bk1[q] = 0xFFFFFFFFFFFFFFFFull; }
  int jbase = split*CHUNK;
  {
    const float4* src = (const float4*)(xb + (size_t)jbase*64);
    float4* dst = (float4*)xjL;
    #pragma unroll
    for (int u=0; u<8; u++) dst[u*512 + tid] = src[u*512 + tid];
    if (tid < CHUNK) sqL[tid] = sq ? sqb[jbase + tid] : 0.f;
  }
  __syncthreads();
  int jl0 = half*128;
  #pragma unroll 1
  for (int jj=0; jj<128; jj++){
    int jl = jl0 + jj;
    const f32x4* xj4 = (const f32x4*)(xjL + jl*64);
    f32x2 a01_0 = {0.f, 0.f}, a23_0 = {0.f, 0.f};
    f32x2 a01_1 = {0.f, 0.f}, a23_1 = {0.f, 0.f};
    #pragma unroll
    for (int q=0;q<16;q++){
      f32x4 v = xj4[q];
      f32x2 vlo = __builtin_shufflevector(v, v, 0, 1);
      f32x2 vhi = __builtin_shufflevector(v, v, 2, 3);
      a01_0 = __builtin_elementwise_fma(__builtin_shufflevector(xi0[q], xi0[q], 0, 1), vlo, a01_0);
      a23_0 = __builtin_elementwise_fma(__builtin_shufflevector(xi0[q], xi0[q], 2, 3), vhi, a23_0);
      a01_1 = __builtin_elementwise_fma(__builtin_shufflevector(xi1[q], xi1[q], 0, 1), vlo, a01_1);
      a23_1 = __builtin_elementwise_fma(__builtin_shufflevector(xi1[q], xi1[q], 2, 3), vhi, a23_1);
    }
    float sqj = sqL[jl];
    int j = jbase + jl;
    float dot0 = (a01_0.x + a01_0.y) + (a23_0.x + a23_0.y);
    float dot1 = (a01_1.x + a01_1.y) + (a23_1.x + a23_1.y);
    float d0 = fmaxf(sqi0 + sqj - 2.f*dot0, 0.f);
    float d1 = fmaxf(sqi1 + sqj - 2.f*dot1, 0.f);
    unsigned long long key0 = ((unsigned long long)__float_as_uint(d0) << 32)
                            | (unsigned)j;
    unsigned long long key1 = ((unsigned long long)__float_as_uint(d1) << 32)
                            | (unsigned)j;
    topk_insert9u(key0, bk0);
    topk_insert9u(key1, bk1);
  }
  __syncthreads();
  unsigned long long* mL = (unsigned long long*)xjL;
  if (half == 1){
    #pragma unroll
    for (int q=0;q<9;q++){
      mL[(size_t)(li*2+0)*9+q] = bk0[q];
      mL[(size_t)(li*2+1)*9+q] = bk1[q];
    }
  }
  __syncthreads();
  if (half == 0){
    #pragma unroll
    for (int q=0;q<9;q++) topk_insert9u(mL[(size_t)(li*2+0)*9+q], bk0);
    #pragma unroll
    for (int q=0;q<9;q++) topk_insert9u(mL[(size_t)(li*2+1)*9+q], bk1);
    size_t base0 = (((size_t)(b*NN + i0))*SPLIT + split)*9;
    size_t base1 = (((size_t)(b*NN + i1))*SPLIT + split)*9;
    #pragma unroll
    for (int q=0;q<9;q++){
      pd[base0+q] = __uint_as_float((unsigned)(bk0[q] >> 32));
      pi_[base0+q] = (int)(unsigned)(bk0[q] & 0xFFFFFFFFull);
      pd[base1+q] = __uint_as_float((unsigned)(bk1[q] >> 32));
      pi_[base1+q] = (int)(unsigned)(bk1[q] & 0xFFFFFFFFull);
    }
  }
}

__global__ __launch_bounds__(512) __attribute__((amdgpu_waves_per_eu(2, 2)))
void k_knn(const float* __restrict__ xn,
           const float* __restrict__ sq,
           float* __restrict__ pd, int* __restrict__ pi_){
  __shared__ __align__(16) float xjL[CHUNK*64];   /* 64 KB */
  __shared__ float sqL[CHUNK];
  knn_body(blockIdx.x, threadIdx.x, xn, sq, pd, pi_, xjL, sqL);
}

// t-looped knn: kept for reference; measured +6us vs split launches (r17).
__global__ __launch_bounds__(512) __attribute__((amdgpu_waves_per_eu(2, 2)))
void k_knn2(const float* __restrict__ xn0, const float* __restrict__ xn1,
            const float* __restrict__ sq0, const float* __restrict__ sq1,
            float* __restrict__ pd0, float* __restrict__ pd1,
            int* __restrict__ pi0, int* __restrict__ pi1){
  __shared__ __align__(16) float xjL[CHUNK*64];   /* 64 KB */
  __shared__ float sqL[CHUNK];
  knn_body(blockIdx.x, threadIdx.x, xn0, sq0, pd0, pi0, xjL, sqL);
  __syncthreads();
  knn_body(blockIdx.x, threadIdx.x, xn1, sq1, pd1, pi1, xjL, sqL);
}

// ---------------- edge1 body: fused merge + edge-GEMM stats (+Yg store) ----------
__device__ __forceinline__ void edge1_body(int bx, int tid,
    const float* __restrict__ h, const float* __restrict__ pd,
    const int* __restrict__ pi_, const float* __restrict__ Wg,
    const float* __restrict__ bg, int* __restrict__ idxf,
    float* __restrict__ part, float* __restrict__ Yg, int storeYg,
    float* dxAll, float* xiAll, float* sSum, float* sSq){
  int lane = tid & 63, wv = tid >> 6;
  float* dxW = dxAll + wv*576;
  float* xiW = xiAll + wv*64;
  int c0 = lane, c1 = lane + 64;
  float bias0 = bg[c0], bias1 = bg[c1];
  float sm0=0.f, ss0=0.f, sm1=0.f, ss1=0.f;
  for (int u4=0; u4<4; u4++){
    int node = bx*16 + wv*4 + u4;
    int b = node >> 12;
    size_t cb = (size_t)node*(SPLIT*9);
    float d0 = pd[cb+lane], d1 = pd[cb+64+lane], d2 = INFINITY;
    int   j0 = pi_[cb+lane], j1 = pi_[cb+64+lane], j2 = 0x7fffffff;
    if (lane < 16){ d2 = pd[cb+128+lane]; j2 = pi_[cb+128+lane]; }
    int kidx[9];
    #pragma unroll
    for (int s=0; s<9; s++){
      float ld = d0; int lj = j0;
      if (d1 < ld || (d1 == ld && j1 < lj)){ ld = d1; lj = j1; }
      if (d2 < ld || (d2 == ld && j2 < lj)){ ld = d2; lj = j2; }
      #pragma unroll
      for (int off=1; off<64; off<<=1){
        float od = __shfl_xor(ld, off, 64);
        int   oj = __shfl_xor(lj, off, 64);
        if (od < ld || (od == ld && oj < lj)){ ld = od; lj = oj; }
      }
      kidx[s] = lj & (NN-1);
      if (lane == 0) idxf[(size_t)node*9 + s] = lj & (NN-1);
      if (j0 == lj){ d0 = INFINITY; j0 = 0x7fffffff; }
      if (j1 == lj){ d1 = INFINITY; j1 = 0x7fffffff; }
      if (j2 == lj){ d2 = INFINITY; j2 = 0x7fffffff; }
    }
    float xi_l = h[(size_t)node*64 + lane];
    xiW[lane] = xi_l;
    #pragma unroll
    for (int k=0; k<9; k++)
      dxW[k*64+lane] = h[((size_t)(b*NN + kidx[k]))*64 + lane] - xi_l;
    float common0 = bias0, common1 = bias1;
    const float4* xi4 = (const float4*)xiW;
    #pragma unroll 4
    for (int d4=0; d4<16; d4++){
      float4 xv = xi4[d4];
      int d = d4*4;
      common0 = fmaf(xv.x, Wg[(d+0)*C2+c0], common0);
      common0 = fmaf(xv.y, Wg[(d+1)*C2+c0], common0);
      common0 = fmaf(xv.z, Wg[(d+2)*C2+c0], common0);
      common0 = fmaf(xv.w, Wg[(d+3)*C2+c0], common0);
      common1 = fmaf(xv.x, Wg[(d+0)*C2+c1], common1);
      common1 = fmaf(xv.y, Wg[(d+1)*C2+c1], common1);
      common1 = fmaf(xv.z, Wg[(d+2)*C2+c1], common1);
      common1 = fmaf(xv.w, Wg[(d+3)*C2+c1], common1);
    }
    float a0[9], a1[9];
    #pragma unroll
    for (int k=0;k<9;k++){ a0[k]=0.f; a1[k]=0.f; }
    const float4* dx4 = (const float4*)dxW;
    for (int d4=0; d4<16; d4++){
      int d = d4*4;
      float w0v[4], w1v[4];
      #pragma unroll
      for (int i=0;i<4;i++){
        w0v[i] = Wg[(64+d+i)*C2+c0];
        w1v[i] = Wg[(64+d+i)*C2+c1];
      }
      #pragma unroll
      for (int k=0;k<9;k++){
        float4 dx = dx4[k*16+d4];
        a0[k] = fmaf(dx.x, w0v[0], a0[k]);
        a0[k] = fmaf(dx.y, w0v[1], a0[k]);
        a0[k] = fmaf(dx.z, w0v[2], a0[k]);
        a0[k] = fmaf(dx.w, w0v[3], a0[k]);
        a1[k] = fmaf(dx.x, w1v[0], a1[k]);
        a1[k] = fmaf(dx.y, w1v[1], a1[k]);
        a1[k] = fmaf(dx.z, w1v[2], a1[k]);
        a1[k] = fmaf(dx.w, w1v[3], a1[k]);
      }
    }
    #pragma unroll
    for (int k=0;k<9;k++){
      float v0 = common0 + a0[k], v1 = common1 + a1[k];
      sm0 += v0; ss0 += v0*v0; sm1 += v1; ss1 += v1*v1;
      if (storeYg){
        size_t yb = ((size_t)node*9 + k)*C2;
        Yg[yb + c0] = v0;
        Yg[yb + c1] = v1;
      }
    }
  }
  sSum[wv*128+lane] = sm0; sSum[wv*128+64+lane] = sm1;
  sSq [wv*128+lane] = ss0; sSq [wv*128+64+lane] = ss1;
  __syncthreads();
  if (tid < 128){
    float sm = sSum[tid]+sSum[128+tid]+sSum[256+tid]+sSum[384+tid];
    float ss = sSq[tid]+sSq[128+tid]+sSq[256+tid]+sSq[384+tid];
    part[bx*256 + tid] = sm;
    part[bx*256 + 128 + tid] = ss;
  }
}

__global__ __launch_bounds__(256) void k_edge1(const float* __restrict__ h,
                        const float* __restrict__ pd, const int* __restrict__ pi_,
                        const float* __restrict__ Wg, const float* __restrict__ bg,
                        int* __restrict__ idxf, float* __restrict__ part,
                        float* __restrict__ Yg, int storeYg){
  __shared__ float dxAll[4*576];
  __shared__ float xiAll[4*64];
  __shared__ float sSum[512], sSq[512];
  edge1_body(blockIdx.x, threadIdx.x, h, pd, pi_, Wg, bg, idxf, part, Yg, storeYg,
             dxAll, xiAll, sSum, sSq);
}

__global__ __launch_bounds__(256) void k_edge1M(
    const float* __restrict__ h0, const float* __restrict__ h1,
    const float* __restrict__ pd0, const float* __restrict__ pd1,
    const int* __restrict__ pi0, const int* __restrict__ pi1,
    const float* __restrict__ Wgb, const float* __restrict__ bgb,
    int* __restrict__ idxf0, int* __restrict__ idxf1,
    float* __restrict__ part0, float* __restrict__ part1,
    float* __restrict__ Yg0, float* __restrict__ Yg1){
  __shared__ float dxAll[4*576];
  __shared__ float xiAll[4*64];
  __shared__ float sSum[512], sSq[512];
  int t  = blockIdx.x >> 9;
  int bx = blockIdx.x & 511;
  edge1_body(bx, threadIdx.x, t ? h1 : h0, t ? pd1 : pd0, t ? pi1 : pi0,
             Wgb + t*C2*C2, bgb + t*C2, t ? idxf1 : idxf0,
             t ? part1 : part0, t ? Yg1 : Yg0, 1,
             dxAll, xiAll, sSum, sSq);
}

// ---------------- edge2m body: inline fin + BN + gelu + max over Yg ---------------
__device__ __forceinline__ void edge2m_body(int bx, int tid,
    const float* __restrict__ Yg, const float* __restrict__ part,
    const float* __restrict__ gg, const float* __restrict__ btg,
    float* __restrict__ gmax, float* scshL, float* s1, float* s2){
  {
    int cc = tid & 127, sl = tid >> 7;
    float sm=0.f, ss=0.f;
    #pragma unroll 4
    for (int u=sl*256; u<sl*256+256; u++){ sm += part[u*256+cc]; ss += part[u*256+128+cc]; }
    s1[tid]=sm; s2[tid]=ss;
  }
  __syncthreads();
  if (tid < 128){
    float sm = s1[tid]+s1[128+tid];
    float ss = s2[tid]+s2[128+tid];
    float mean = sm/(float)RG;
    float var = fmaxf(ss/(float)RG - mean*mean, 0.f);
    float sc = gg[tid]*rsqrtf(var+1e-5f);
    scshL[tid] = sc; scshL[128+tid] = btg[tid] - mean*sc;
  }
  __syncthreads();
  size_t base = (size_t)bx*2048;
  for (int p=0; p<8; p++){
    size_t idx = base + p*256 + tid;
    int c = idx & 127;
    size_t node = idx >> 7;
    float sc = scshL[c], sh = scshL[128+c];
    size_t yb = node*9*C2 + c;
    float m = -INFINITY;
    #pragma unroll
    for (int k=0;k<9;k++){
      m = fmaxf(m, gelu(fmaf(Yg[yb + (size_t)k*C2], sc, sh)));
    }
    gmax[idx] = m;
  }
}

__global__ __launch_bounds__(256) void k_edge2m(const float* __restrict__ Yg,
                        const float* __restrict__ part, const float* __restrict__ gg,
                        const float* __restrict__ btg, float* __restrict__ gmax){
  __shared__ float scshL[256];
  __shared__ float s1[256], s2[256];
  edge2m_body(blockIdx.x, threadIdx.x, Yg, part, gg, btg, gmax, scshL, s1, s2);
}

__global__ __launch_bounds__(256) void k_edge2mM(
    const float* __restrict__ Yg0, const float* __restrict__ Yg1,
    const float* __restrict__ part0, const float* __restrict__ part1,
    const float* __restrict__ ggb, const float* __restrict__ btgb,
    float* __restrict__ gmax0, float* __restrict__ gmax1){
  __shared__ float scshL[256];
  __shared__ float s1[256], s2[256];
  int t  = blockIdx.x >> 9;
  int bx = blockIdx.x & 511;
  edge2m_body(bx, threadIdx.x, t ? Yg1 : Yg0, t ? part1 : part0,
              ggb + t*C2, btgb + t*C2, t ? gmax1 : gmax0, scshL, s1, s2);
}

// ------- edge pass 2 (fallback): inline fin + recompute + BN + gelu + max ---------
__global__ __launch_bounds__(256) void k_edge2(const float* __restrict__ h,
                        const int* __restrict__ idxf,
                        const float* __restrict__ Wg, const float* __restrict__ bg,
                        const float* __restrict__ part, const float* __restrict__ gg,
                        const float* __restrict__ btg, float* __restrict__ gmax){
  __shared__ float dxAll[4*576];
  __shared__ float xiAll[4*64];
  __shared__ float scshL[256];
  __shared__ float s1[256], s2[256];
  int tid = threadIdx.x, lane = tid & 63, wv = tid >> 6;
  {
    int cc = tid & 127, sl = tid >> 7;
    float sm=0.f, ss=0.f;
    #pragma unroll 4
    for (int u=sl*256; u<sl*256+256; u++){ sm += part[u*256+cc]; ss += part[u*256+128+cc]; }
    s1[tid]=sm; s2[tid]=ss;
  }
  __syncthreads();
  if (tid < 128){
    float sm = s1[tid]+s1[128+tid];
    float ss = s2[tid]+s2[128+tid];
    float mean = sm/(float)RG;
    float var = fmaxf(ss/(float)RG - mean*mean, 0.f);
    float sc = gg[tid]*rsqrtf(var+1e-5f);
    scshL[tid] = sc; scshL[128+tid] = btg[tid] - mean*sc;
  }
  __syncthreads();
  float* dxW = dxAll + wv*576;
  float* xiW = xiAll + wv*64;
  int c0 = lane, c1 = lane + 64;
  float bias0 = bg[c0], bias1 = bg[c1];
  float sc0 = scshL[c0], sh0 = scshL[128+c0];
  float sc1 = scshL[c1], sh1 = scshL[128+c1];
  for (int u4=0; u4<4; u4++){
    int node = blockIdx.x*16 + wv*4 + u4;
    int b = node >> 12;
    int kidx[9];
    #pragma unroll
    for (int k=0;k<9;k++) kidx[k] = idxf[(size_t)node*9 + k] & (NN-1);
    float xi_l = h[(size_t)node*64 + lane];
    xiW[lane] = xi_l;
    #pragma unroll
    for (int k=0; k<9; k++)
      dxW[k*64+lane] = h[((size_t)(b*NN + kidx[k]))*64 + lane] - xi_l;
    float common0 = bias0, common1 = bias1;
    for (int d=0; d<64; d++){
      float xv = xiW[d];
      common0 = fmaf(xv, Wg[d*C2+c0], common0);
      common1 = fmaf(xv, Wg[d*C2+c1], common1);
    }
    float a0[9], a1[9];
    #pragma unroll
    for (int k=0;k<9;k++){ a0[k]=0.f; a1[k]=0.f; }
    for (int d=0; d<64; d++){
      float w0 = Wg[(64+d)*C2+c0], w1 = Wg[(64+d)*C2+c1];
      #pragma unroll
      for (int k=0;k<9;k++){
        float dxv = dxW[k*64+d];
        a0[k] = fmaf(dxv, w0, a0[k]);
        a1[k] = fmaf(dxv, w1, a1[k]);
      }
    }
    float m0 = -INFINITY, m1 = -INFINITY;
    #pragma unroll
    for (int k=0;k<9;k++){
      m0 = fmaxf(m0, gelu(fmaf(common0 + a0[k], sc0, sh0)));
      m1 = fmaxf(m1, gelu(fmaf(common1 + a1[k], sc1, sh1)));
    }
    gmax[(size_t)node*C2 + c0] = m0;
    gmax[(size_t)node*C2 + c1] = m1;
  }
}

// ---------------- FFN1 body ----------------
__device__ __forceinline__ void ffn1_body(int bx, int tid,
    const float* __restrict__ Y2, const float* __restrict__ part,
    const float* __restrict__ g2, const float* __restrict__ bt2,
    const float* __restrict__ x0f, float* __restrict__ outt,
    const float* __restrict__ Wf1, const float* __restrict__ bf1,
    float* __restrict__ partB, float* scshL, float* otT, float* s1, float* s2){
  int r0 = bx*32;
  {
    int c = tid & 63, sl = tid >> 6;
    float sm=0.f, ss=0.f;
    #pragma unroll 4
    for (int u=sl*64; u<sl*64+64; u++){ sm += part[u*128+c]; ss += part[u*128+64+c]; }
    s1[tid]=sm; s2[tid]=ss;
  }
  __syncthreads();
  if (tid < 64){
    float sm = s1[tid]+s1[64+tid]+s1[128+tid]+s1[192+tid];
    float ss = s2[tid]+s2[64+tid]+s2[128+tid]+s2[192+tid];
    float mean = sm/(float)R1;
    float var = fmaxf(ss/(float)R1 - mean*mean, 0.f);
    float sc = g2[tid]*rsqrtf(var+1e-5f);
    scshL[tid] = sc; scshL[64+tid] = bt2[tid] - mean*sc;
  }
  __syncthreads();
  #pragma unroll
  for (int p=0; p<8; p++){
    int idx = p*256 + tid;
    int lr = idx >> 6, cc = idx & 63;
    size_t gi = (size_t)(r0+lr)*64 + cc;
    float v = fmaf(Y2[gi], scshL[cc], scshL[64+cc]) + x0f[gi];
    otT[cc*36 + lr] = v;
    outt[gi] = v;
  }
  __syncthreads();
  int tx = tid & 63, ty = tid >> 6;
  int c = tx*4, r = ty*8;
  float acc[8][4];
  #pragma unroll
  for (int i=0;i<8;i++){
    #pragma unroll
    for (int j=0;j<4;j++) acc[i][j]=0.f;
  }
  for (int d=0; d<64; d++){
    float4 xa = *(const float4*)&otT[d*36 + r];
    float4 xb = *(const float4*)&otT[d*36 + r + 4];
    float4 wv = *(const float4*)(Wf1 + d*256 + c);
    float xs[8] = {xa.x,xa.y,xa.z,xa.w, xb.x,xb.y,xb.z,xb.w};
    #pragma unroll
    for (int i=0;i<8;i++){
      acc[i][0] = fmaf(xs[i], wv.x, acc[i][0]);
      acc[i][1] = fmaf(xs[i], wv.y, acc[i][1]);
      acc[i][2] = fmaf(xs[i], wv.z, acc[i][2]);
      acc[i][3] = fmaf(xs[i], wv.w, acc[i][3]);
    }
  }
  float4 bz = *(const float4*)(bf1 + c);
  float bzv[4] = {bz.x, bz.y, bz.z, bz.w};
  #pragma unroll
  for (int j=0;j<4;j++){
    float cs=0.f, cq=0.f;
    #pragma unroll
    for (int i=0;i<8;i++){
      float v = acc[i][j] + bzv[j];
      cs += v; cq += v*v;
    }
    s1[(c+j)*4 + ty] = cs;
    s2[(c+j)*4 + ty] = cq;
  }
  __syncthreads();
  {
    float sm = s1[tid*4]+s1[tid*4+1]+s1[tid*4+2]+s1[tid*4+3];
    float ss = s2[tid*4]+s2[tid*4+1]+s2[tid*4+2]+s2[tid*4+3];
    partB[bx*512 + tid] = sm;
    partB[bx*512 + 256 + tid] = ss;
  }
}

__global__ void k_ffn1_fused(const float* __restrict__ Y2, const float* __restrict__ part,
                             const float* __restrict__ g2, const float* __restrict__ bt2,
                             const float* __restrict__ x0f, float* __restrict__ outt,
                             const float* __restrict__ Wf1, const float* __restrict__ bf1,
                             float* __restrict__ partB){
  __shared__ float scshL[128];
  __shared__ float otT[64*36];
  __shared__ float s1[1024], s2[1024];
  ffn1_body(blockIdx.x, threadIdx.x, Y2, part, g2, bt2, x0f, outt, Wf1, bf1,
            partB, scshL, otT, s1, s2);
}

__global__ void k_ffn1M(const float* __restrict__ Y2_0, const float* __restrict__ Y2_1,
                        const float* __restrict__ part0, const float* __restrict__ part1,
                        const float* __restrict__ g2b, const float* __restrict__ bt2b,
                        const float* __restrict__ x0f,
                        float* __restrict__ outt0, float* __restrict__ outt1,
                        const float* __restrict__ Wf1b, const float* __restrict__ bf1b,
                        float* __restrict__ partB0, float* __restrict__ partB1){
  __shared__ float scshL[128];
  __shared__ float otT[64*36];
  __shared__ float s1[1024], s2[1024];
  int t  = blockIdx.x >> 8;
  int bx = blockIdx.x & 255;
  ffn1_body(bx, threadIdx.x, t ? Y2_1 : Y2_0, t ? part1 : part0,
            g2b + t*64, bt2b + t*64, x0f, t ? outt1 : outt0,
            Wf1b + t*CCH*C4, bf1b + t*C4, t ? partB1 : partB0,
            scshL, otT, s1, s2);
}

// ---------------- FFN2 body ----------------
__device__ __forceinline__ void ffn2_body(int bx, int tid,
    const float* __restrict__ outt, const float* __restrict__ Wf1,
    const float* __restrict__ bf1, const float* __restrict__ partB,
    const float* __restrict__ gf1, const float* __restrict__ btf1,
    const float* __restrict__ Wf2, const float* __restrict__ bf2,
    float* __restrict__ Yf2, float* __restrict__ partA,
    float* scshL, float* otT, float* fT, float* s1, float* s2){
  int r0 = bx*32;
  {
    float sm=0.f, ss=0.f;
    #pragma unroll 4
    for (int u=0; u<256; u++){ sm += partB[u*512+tid]; ss += partB[u*512+256+tid]; }
    float mean = sm/(float)R1;
    float var = fmaxf(ss/(float)R1 - mean*mean, 0.f);
    float sc = gf1[tid]*rsqrtf(var+1e-5f);
    scshL[tid] = sc; scshL[256+tid] = btf1[tid] - mean*sc;
  }
  #pragma unroll
  for (int p=0; p<8; p++){
    int idx = p*256 + tid;
    int lr = idx >> 6, cc = idx & 63;
    otT[cc*36 + lr] = outt[(size_t)r0*64 + idx];
  }
  __syncthreads();
  int tx = tid & 63, ty = tid >> 6;
  int c = tx*4, r = ty*8;
  {
    float acc[8][4];
    #pragma unroll
    for (int i=0;i<8;i++){
      #pragma unroll
      for (int j=0;j<4;j++) acc[i][j]=0.f;
    }
    for (int d=0; d<64; d++){
      float4 xa = *(const float4*)&otT[d*36 + r];
      float4 xb = *(const float4*)&otT[d*36 + r + 4];
      float4 wv = *(const float4*)(Wf1 + d*256 + c);
      float xs[8] = {xa.x,xa.y,xa.z,xa.w, xb.x,xb.y,xb.z,xb.w};
      #pragma unroll
      for (int i=0;i<8;i++){
        acc[i][0] = fmaf(xs[i], wv.x, acc[i][0]);
        acc[i][1] = fmaf(xs[i], wv.y, acc[i][1]);
        acc[i][2] = fmaf(xs[i], wv.z, acc[i][2]);
        acc[i][3] = fmaf(xs[i], wv.w, acc[i][3]);
      }
    }
    float4 bz = *(const float4*)(bf1 + c);
    float bzv[4] = {bz.x, bz.y, bz.z, bz.w};
    #pragma unroll
    for (int j=0;j<4;j++){
      float sc = scshL[c+j], sh = scshL[256+c+j];
      #pragma unroll
      for (int i=0;i<8;i++){
        float v = gelu(fmaf(acc[i][j] + bzv[j], sc, sh));
        fT[(c+j)*36 + r + i] = v;
      }
    }
  }
  __syncthreads();
  int tx2 = tid & 15, ty2 = tid >> 4;
  int c2 = tx2*4, r2 = ty2*2;
  float acc2[2][4];
  #pragma unroll
  for (int i=0;i<2;i++){
    #pragma unroll
    for (int j=0;j<4;j++) acc2[i][j]=0.f;
  }
  for (int d=0; d<256; d++){
    float2 xv = *(const float2*)&fT[d*36 + r2];
    float4 wv = *(const float4*)(Wf2 + d*64 + c2);
    acc2[0][0] = fmaf(xv.x, wv.x, acc2[0][0]);
    acc2[0][1] = fmaf(xv.x, wv.y, acc2[0][1]);
    acc2[0][2] = fmaf(xv.x, wv.z, acc2[0][2]);
    acc2[0][3] = fmaf(xv.x, wv.w, acc2[0][3]);
    acc2[1][0] = fmaf(xv.y, wv.x, acc2[1][0]);
    acc2[1][1] = fmaf(xv.y, wv.y, acc2[1][1]);
    acc2[1][2] = fmaf(xv.y, wv.z, acc2[1][2]);
    acc2[1][3] = fmaf(xv.y, wv.w, acc2[1][3]);
  }
  float4 b2 = *(const float4*)(bf2 + c2);
  float b2v[4] = {b2.x, b2.y, b2.z, b2.w};
  float out0[4], out1[4];
  #pragma unroll
  for (int j=0;j<4;j++){
    out0[j] = acc2[0][j] + b2v[j];
    out1[j] = acc2[1][j] + b2v[j];
    s1[(c2+j)*16 + ty2] = out0[j] + out1[j];
    s2[(c2+j)*16 + ty2] = out0[j]*out0[j] + out1[j]*out1[j];
  }
  *(float4*)&Yf2[(size_t)(r0+r2)*64 + c2]   = make_float4(out0[0],out0[1],out0[2],out0[3]);
  *(float4*)&Yf2[(size_t)(r0+r2+1)*64 + c2] = make_float4(out1[0],out1[1],out1[2],out1[3]);
  __syncthreads();
  if (tid < 64){
    float sm=0.f, ss=0.f;
    #pragma unroll
    for (int q=0;q<16;q++){ sm += s1[tid*16+q]; ss += s2[tid*16+q]; }
    partA[bx*128 + tid] = sm;
    partA[bx*128 + 64 + tid] = ss;
  }
}

__global__ void k_ffn2_fused(const float* __restrict__ outt, const float* __restrict__ Wf1,
                             const float* __restrict__ bf1, const float* __restrict__ partB,
                             const float* __restrict__ gf1, const float* __restrict__ btf1,
                             const float* __restrict__ Wf2, const float* __restrict__ bf2,
                             float* __restrict__ Yf2, float* __restrict__ partA){
  __shared__ float scshL[512];
  __shared__ float otT[64*36];
  __shared__ float fT[256*36];
  __shared__ float s1[1024], s2[1024];
  ffn2_body(blockIdx.x, threadIdx.x, outt, Wf1, bf1, partB, gf1, btf1, Wf2, bf2,
            Yf2, partA, scshL, otT, fT, s1, s2);
}

__global__ void k_ffn2M(const float* __restrict__ outt0, const float* __restrict__ outt1,
                        const float* __restrict__ Wf1b, const float* __restrict__ bf1b,
                        const float* __restrict__ partB0, const float* __restrict__ partB1,
                        const float* __restrict__ gf1b, const float* __restrict__ btf1b,
                        const float* __restrict__ Wf2b, const float* __restrict__ bf2b,
                        float* __restrict__ Yf2_0, float* __restrict__ Yf2_1,
                        float* __restrict__ partA0, float* __restrict__ partA1){
  __shared__ float scshL[512];
  __shared__ float otT[64*36];
  __shared__ float fT[256*36];
  __shared__ float s1[1024], s2[1024];
  int t  = blockIdx.x >> 8;
  int bx = blockIdx.x & 255;
  ffn2_body(bx, threadIdx.x, t ? outt1 : outt0, Wf1b + t*CCH*C4, bf1b + t*C4,
            t ? partB1 : partB0, gf1b + t*C4, btf1b + t*C4,
            Wf2b + t*C4*CCH, bf2b + t*64, t ? Yf2_1 : Yf2_0,
            t ? partA1 : partA0, scshL, otT, fT, s1, s2);
}

// ---------------- final body ----------------
__device__ __forceinline__ void final_body(int bx, int tid,
    const float* __restrict__ Yf2, const float* __restrict__ partA,
    const float* __restrict__ gf2, const float* __restrict__ btf2,
    const float* __restrict__ outt, float* __restrict__ feat,
    float* scshL, float* s1, float* s2){
  {
    int c = tid & 63, sl = tid >> 6;
    float sm=0.f, ss=0.f;
    #pragma unroll 4
    for (int u=sl*64; u<sl*64+64; u++){ sm += partA[u*128+c]; ss += partA[u*128+64+c]; }
    s1[tid]=sm; s2[tid]=ss;
  }
  __syncthreads();
  if (tid < 64){
    float sm = s1[tid]+s1[64+tid]+s1[128+tid]+s1[192+tid];
    float ss = s2[tid]+s2[64+tid]+s2[128+tid]+s2[192+tid];
    float mean = sm/(float)R1;
    float var = fmaxf(ss/(float)R1 - mean*mean, 0.f);
    float sc = gf2[tid]*rsqrtf(var+1e-5f);
    scshL[tid] = sc; scshL[64+tid] = btf2[tid] - mean*sc;
  }
  __syncthreads();
  size_t base = (size_t)bx*2048;
  for (int p=0; p<8; p++){
    size_t idx = base + p*256 + tid;
    int cc = idx & 63;
    feat[idx] = fmaf(Yf2[idx], scshL[cc], scshL[64+cc]) + outt[idx];
  }
}

__global__ void k_final(const float* __restrict__ Yf2, const float* __restrict__ partA,
                        const float* __restrict__ gf2, const float* __restrict__ btf2,
                        const float* __restrict__ outt, float* __restrict__ feat){
  __shared__ float scshL[128];
  __shared__ float s1[256], s2[256];
  final_body(blockIdx.x, threadIdx.x, Yf2, partA, gf2, btf2, outt, feat, scshL, s1, s2);
}

__global__ void k_finalM(const float* __restrict__ Yf2_0, const float* __restrict__ Yf2_1,
                         const float* __restrict__ partA0, const float* __restrict__ partA1,
                         const float* __restrict__ gf2b, const float* __restrict__ btf2b,
                         const float* __restrict__ outt0, const float* __restrict__ outt1,
                         float* __restrict__ f0, float* __restrict__ f1){
  __shared__ float scshL[128];
  __shared__ float s1[256], s2[256];
  int t  = blockIdx.x >> 8;
  int bx = blockIdx.x & 255;
  final_body(bx, threadIdx.x, t ? Yf2_1 : Yf2_0, t ? partA1 : partA0,
             gf2b + t*64, btf2b + t*64, t ? outt1 : outt0,
             t ? f1 : f0, scshL, s1, s2);
}

// ----- finalmix: BNf2+residual for BOTH t, alpha-mix, transposed write -> out -----
__global__ void k_finalmix(const float* __restrict__ Yf2_0, const float* __restrict__ Yf2_1,
                           const float* __restrict__ partA0, const float* __restrict__ partA1,
                           const float* __restrict__ gf2b, const float* __restrict__ btf2b,
                           const float* __restrict__ outt0, const float* __restrict__ outt1,
                           const float* __restrict__ alpha, float* __restrict__ outv){
  __shared__ float scsh0[128], scsh1[128];
  __shared__ float s1[256], s2[256];
  __shared__ float tile0[64*33], tile1[64*33];
  int tid = threadIdx.x, bx = blockIdx.x;
  {
    int c = tid & 63, sl = tid >> 6;
    float sm=0.f, ss=0.f;
    #pragma unroll 4
    for (int u=sl*64; u<sl*64+64; u++){ sm += partA0[u*128+c]; ss += partA0[u*128+64+c]; }
    s1[tid]=sm; s2[tid]=ss;
  }
  __syncthreads();
  if (tid < 64){
    float sm = s1[tid]+s1[64+tid]+s1[128+tid]+s1[192+tid];
    float ss = s2[tid]+s2[64+tid]+s2[128+tid]+s2[192+tid];
    float mean = sm/(float)R1;
    float var = fmaxf(ss/(float)R1 - mean*mean, 0.f);
    float sc = gf2b[tid]*rsqrtf(var+1e-5f);
    scsh0[tid] = sc; scsh0[64+tid] = btf2b[tid] - mean*sc;
  }
  __syncthreads();
  {
    int c = tid & 63, sl = tid >> 6;
    float sm=0.f, ss=0.f;
    #pragma unroll 4
    for (int u=sl*64; u<sl*64+64; u++){ sm += partA1[u*128+c]; ss += partA1[u*128+64+c]; }
    s1[tid]=sm; s2[tid]=ss;
  }
  __syncthreads();
  if (tid < 64){
    float sm = s1[tid]+s1[64+tid]+s1[128+tid]+s1[192+tid];
    float ss = s2[tid]+s2[64+tid]+s2[128+tid]+s2[192+tid];
    float mean = sm/(float)R1;
    float var = fmaxf(ss/(float)R1 - mean*mean, 0.f);
    float sc = gf2b[64+tid]*rsqrtf(var+1e-5f);
    scsh1[tid] = sc; scsh1[64+tid] = btf2b[64+tid] - mean*sc;
  }
  __syncthreads();
  size_t base = (size_t)bx*2048;
  #pragma unroll
  for (int p=0; p<8; p++){
    size_t idx = base + p*256 + tid;
    int cc = idx & 63;
    int nl = (int)((idx >> 6) & 31);
    float f0v = fmaf(Yf2_0[idx], scsh0[cc], scsh0[64+cc]) + outt0[idx];
    float f1v = fmaf(Yf2_1[idx], scsh1[cc], scsh1[64+cc]) + outt1[idx];
    tile0[cc*33 + nl] = f0v;
    tile1[cc*33 + nl] = f1v;
  }
  __syncthreads();
  int b  = bx >> 7;
  int n0 = (bx & 127) * 32;
  float a00 = alpha[0], a01 = alpha[1];
  float a10 = alpha[TT], a11 = alpha[TT+1];
  #pragma unroll
  for (int q=0; q<2; q++){
    int slot = tid + q*256;
    int c  = slot >> 3;
    int f4 = slot & 7;
    float v0[4], v1[4];
    #pragma unroll
    for (int k2=0;k2<4;k2++){
      v0[k2] = tile0[c*33 + f4*4 + k2];
      v1[k2] = tile1[c*33 + f4*4 + k2];
    }
    size_t o0 = ((size_t)((0*BB + b)*CCH + c))*NN + n0 + f4*4;
    size_t o1 = ((size_t)((1*BB + b)*CCH + c))*NN + n0 + f4*4;
    *(float4*)&outv[o0] = make_float4(a00*v0[0] + a01*v1[0], a00*v0[1] + a01*v1[1],
                                      a00*v0[2] + a01*v1[2], a00*v0[3] + a01*v1[3]);
    *(float4*)&outv[o1] = make_float4(a10*v0[0] + a11*v1[0], a10*v0[1] + a11*v1[1],
                                      a10*v0[2] + a11*v1[2], a10*v0[3] + a11*v1[3]);
  }
}

// ---------------- alpha-mix + transpose -> output (T,B,C,N) fp32 ----------------
__global__ void k_mix(const float* __restrict__ f0, const float* __restrict__ f1,
                      const float* __restrict__ alpha, float* __restrict__ outv){
  int idx = blockIdx.x*256 + threadIdx.x;
  if (idx >= TT*BB*CCH*NN) return;
  int n = idx & (NN-1);
  int c = (idx >> 12) & 63;
  int b = (idx >> 18) & 1;
  int i = idx >> 19;
  float a0 = alpha[i*TT + 0];
  float a1 = alpha[i*TT + 1];
  size_t fi = ((size_t)(b*NN + n))*64 + c;
  outv[idx] = a0*f0[fi] + a1*f1[fi];
}

extern "C" void kernel_launch(void* const* d_in, const int* in_sizes, int n_in,
                              void* d_out, int out_size, void* d_ws, size_t ws_size,
                              hipStream_t stream){
  float* outp = (float*)d_out;

  static const int expect[22] = {
    524288, 8192, 128, 128, 128, 32768, 256, 256, 256, 16384, 128, 128, 128,
    32768, 512, 512, 512, 32768, 128, 128, 128, 4
  };
  bool ok = (n_in == 22) && (out_size == TT*BB*CCH*NN) &&
            (ws_size >= WS_TOTAL*sizeof(float));
  if (ok){
    for (int i=0;i<22;i++) if (in_sizes[i] != expect[i]) { ok = false; break; }
  }
  if (!ok){
    k_zero<<<(out_size+255)/256,256,0,stream>>>(outp, out_size);
    return;
  }
  const bool bigws   = (ws_size >= WS_BIG*sizeof(float));
  const bool merged  = (ws_size >= WS_M1*sizeof(float));
  const bool merged2 = (ws_size >= WS_M2*sizeof(float));
  const bool merged3 = (ws_size >= WS_M3*sizeof(float));

  const float* x   = (const float*)d_in[0];
  const float* W1  = (const float*)d_in[1];
  const float* b1  = (const float*)d_in[2];
  const float* g1  = (const float*)d_in[3];
  const float* bt1 = (const float*)d_in[4];
  const float* Wg  = (const float*)d_in[5];
  const float* bg  = (const float*)d_in[6];
  const float* gg  = (const float*)d_in[7];
  const float* btg = (const float*)d_in[8];
  const float* W2  = (const float*)d_in[9];
  const float* b2v = (const float*)d_in[10];
  const float* g2  = (const float*)d_in[11];
  const float* bt2 = (const float*)d_in[12];
  const float* Wf1 = (const float*)d_in[13];
  const float* bf1v= (const float*)d_in[14];
  const float* gf1 = (const float*)d_in[15];
  const float* btf1= (const float*)d_in[16];
  const float* Wf2 = (const float*)d_in[17];
  const float* bf2v= (const float*)d_in[18];
  const float* gf2 = (const float*)d_in[19];
  const float* btf2= (const float*)d_in[20];
  const float* alpha=(const float*)d_in[21];
  float* ws = (float*)d_ws;

  float* x0f  = ws + 0;
  float* hbuf = ws + 524288;
  float* xnb  = ws + 1048576;
  float* sqb  = ws + 1572864;
  float* partA= ws + 1581056;
  int*   idxf = (int*)(ws + 1712640);
  float* f0   = ws + 1786368;
  float* f1b  = ws + 2310656;
  float* Rbig = ws + 2834944;
  float* pdist = Rbig;
  int*   pidx  = (int*)(Rbig + (size_t)R1*SPLIT*9);
  float* gmaxb = Rbig;
  float* outt  = Rbig + 1048576;
  float* Y2    = Rbig + 1572864;
  float* partB = Rbig + 2097152;
  float* Yf2   = Rbig;
  float* Yg    = ws + WS_TOTAL;
  /* merged-front tier buffers */
  float* hbuf1  = ws + WS_BIG;
  float* xnb1   = hbuf1 + 524288;
  float* sqb1   = xnb1 + 524288;
  float* partA1 = sqb1 + 8192;
  float* pd1    = partA1 + 32768;
  int*   pi1    = (int*)(pd1 + (size_t)R1*SPLIT*9);
  /* merged-back tier buffers */
  float* gmax1  = ws + WS_M1;
  float* Y2_1   = gmax1 + 1048576;
  float* outt1  = Y2_1 + 524288;
  float* partB1 = outt1 + 524288;
  float* Yf2_1  = partB1 + 131072;
  /* merged-edge tier buffers */
  float* Yg1    = ws + WS_M2;
  int*   idxf1  = (int*)(Yg1 + 9437184);
  float* partE1 = (float*)(idxf1 + 73728);

  k_transpose<<<2048,256,0,stream>>>(x, x0f);
  float* feats[2] = {f0, f1b};
  bool did_mix = false;

  if (merged){
    k_gemm1M<<<512,256,0,stream>>>(x0f, W1, b1, hbuf, hbuf1, partA, partA1);
    k_applynormM<<<512,256,0,stream>>>(hbuf, hbuf1, partA, partA1, g1, bt1,
                                       xnb, xnb1, sqb, sqb1);
    /* knn split: two launches overlap tail/head naturally; in-kernel t-loop
       (k_knn2, r17) serialized phases and cost ~6us. */
    k_knn<<<256,512,0,stream>>>(xnb, sqb, pdist, pidx);
    k_knn<<<256,512,0,stream>>>(xnb1, sqb1, pd1, pi1);
    if (merged3){
      k_edge1M<<<1024,256,0,stream>>>(hbuf, hbuf1, pdist, pd1, pidx, pi1,
                                      Wg, bg, idxf, idxf1, partA, partE1,
                                      Yg, Yg1);
      k_edge2mM<<<1024,256,0,stream>>>(Yg, Yg1, partA, partE1, gg, btg,
                                       gmaxb, gmax1);
      k_gemm2M<<<512,256,0,stream>>>(gmaxb, gmax1, W2, b2v, Y2, Y2_1, partA, partA1);
      k_ffn1M<<<512,256,0,stream>>>(Y2, Y2_1, partA, partA1, g2, bt2, x0f,
                                    outt, outt1, Wf1, bf1v, partB, partB1);
      k_ffn2M<<<512,256,0,stream>>>(outt, outt1, Wf1, bf1v, partB, partB1,
                                    gf1, btf1, Wf2, bf2v, Yf2, Yf2_1, partA, partA1);
      k_finalmix<<<256,256,0,stream>>>(Yf2, Yf2_1, partA, partA1, gf2, btf2,
                                       outt, outt1, alpha, outp);
      did_mix = true;
    } else if (merged2){
      k_edge1<<<512,256,0,stream>>>(hbuf, pdist, pidx, Wg, bg, idxf, partA, Yg, 1);
      k_edge2m<<<512,256,0,stream>>>(Yg, partA, gg, btg, gmaxb);
      k_edge1<<<512,256,0,stream>>>(hbuf1, pd1, pi1, Wg + C2*C2, bg + C2, idxf, partA, Yg, 1);
      k_edge2m<<<512,256,0,stream>>>(Yg, partA, gg + C2, btg + C2, gmax1);
      k_gemm2M<<<512,256,0,stream>>>(gmaxb, gmax1, W2, b2v, Y2, Y2_1, partA, partA1);
      k_ffn1M<<<512,256,0,stream>>>(Y2, Y2_1, partA, partA1, g2, bt2, x0f,
                                    outt, outt1, Wf1, bf1v, partB, partB1);
      k_ffn2M<<<512,256,0,stream>>>(outt, outt1, Wf1, bf1v, partB, partB1,
                                    gf1, btf1, Wf2, bf2v, Yf2, Yf2_1, partA, partA1);
      k_finalM<<<512,256,0,stream>>>(Yf2, Yf2_1, partA, partA1, gf2, btf2,
                                     outt, outt1, f0, f1b);
    } else {
      for (int t=0; t<TT; t++){
        float* h_t  = t ? hbuf1 : hbuf;
        float* pd_t = t ? pd1 : pdist;
        int*   pi_t = t ? pi1 : pidx;
        k_edge1<<<512,256,0,stream>>>(h_t, pd_t, pi_t, Wg + t*C2*C2, bg + t*C2,
                                      idxf, partA, Yg, 1);
        k_edge2m<<<512,256,0,stream>>>(Yg, partA, gg + t*C2, btg + t*C2, gmaxb);
        k_gemm2_stats<<<256,256,0,stream>>>(gmaxb, W2 + t*C2*CCH, b2v + t*64, Y2, partA);
        k_ffn1_fused<<<256,256,0,stream>>>(Y2, partA, g2 + t*64, bt2 + t*64, x0f, outt,
                                           Wf1 + t*CCH*C4, bf1v + t*C4, partB);
        k_ffn2_fused<<<256,256,0,stream>>>(outt, Wf1 + t*CCH*C4, bf1v + t*C4, partB,
                                           gf1 + t*C4, btf1 + t*C4,
                                           Wf2 + t*C4*CCH, bf2v + t*64, Yf2, partA);
        k_final<<<256,256,0,stream>>>(Yf2, partA, gf2 + t*64, btf2 + t*64, outt, feats[t]);
      }
    }
  } else {
    for (int t=0; t<TT; t++){
      k_gemm1_stats<<<256,256,0,stream>>>(x0f, W1 + t*CCH*CCH, b1 + t*64, hbuf, partA);
      k_applynorm3<<<256,256,0,stream>>>(hbuf, partA, g1 + t*64, bt1 + t*64, xnb, sqb);
      k_knn<<<256,512,0,stream>>>(xnb, sqb, pdist, pidx);
      k_edge1<<<512,256,0,stream>>>(hbuf, pdist, pidx, Wg + t*C2*C2, bg + t*C2, idxf, partA,
                                    bigws ? Yg : hbuf, bigws ? 1 : 0);
      if (bigws){
        k_edge2m<<<512,256,0,stream>>>(Yg, partA, gg + t*C2, btg + t*C2, gmaxb);
      } else {
        k_edge2<<<512,256,0,stream>>>(hbuf, idxf, Wg + t*C2*C2, bg + t*C2,
                                      partA, gg + t*C2, btg + t*C2, gmaxb);
      }
      k_gemm2_stats<<<256,256,0,stream>>>(gmaxb, W2 + t*C2*CCH, b2v + t*64, Y2, partA);
      k_ffn1_fused<<<256,256,0,stream>>>(Y2, partA, g2 + t*64, bt2 + t*64, x0f, outt,
                                         Wf1 + t*CCH*C4, bf1v + t*C4, partB);
      k_ffn2_fused<<<256,256,0,stream>>>(outt, Wf1 + t*CCH*C4, bf1v + t*C4, partB,
                                         gf1 + t*C4, btf1 + t*C4,
                                         Wf2 + t*C4*CCH, bf2v + t*64, Yf2, partA);
      k_final<<<256,256,0,stream>>>(Yf2, partA, gf2 + t*64, btf2 + t*64, outt, feats[t]);
    }
  }
  if (!did_mix){
    k_mix<<<4096,256,0,stream>>>(f0, f1b, alpha, outp);
  }
}

// Round 20
// 529.923 us; speedup vs baseline: 1.0641x; 1.0134x over previous
//
#include <hip/hip_runtime.h>
#include <math.h>

#define BB 2
#define CCH 64
#define NN 4096
#define KK 9
#define TT 2
#define C2 128
#define C4 256
#define R1 (BB*NN)        /* 8192  */
#define RG (BB*NN*KK)     /* 73728 */
#define SPLIT 16
#define CHUNK (NN/SPLIT)  /* 256 */

#define WS_TOTAL 5194240ull
#define WS_BIG   (5194240ull + 9437184ull)   /* + Yg (RG*C2) */
#define WS_M1    (WS_BIG + 3448832ull)
#define WS_M2    (WS_M1 + 2752512ull)
#define WS_M3    (WS_M2 + 9641984ull)

typedef float f32x2 __attribute__((ext_vector_type(2)));
typedef float f32x4 __attribute__((ext_vector_type(4)));

__device__ __forceinline__ float gelu(float v){ return 0.5f*v*(1.f + erff(v*0.70710678118654752f)); }

__global__ void k_zero(float* __restrict__ o, int n){
  int i = blockIdx.x*256 + threadIdx.x;
  if (i < n) o[i] = 0.f;
}

// ---------------- transpose x (B,C,N) -> x0f (B,N,C) ----------------
__global__ void k_transpose(const float* __restrict__ x, float* __restrict__ x0f){
  int idx = blockIdx.x*256 + threadIdx.x;
  if (idx >= BB*NN*CCH) return;
  int c = idx & (CCH-1);
  int n = (idx >> 6) & (NN-1);
  int b = idx >> 18;
  x0f[idx] = x[(size_t)(b*CCH + c)*NN + n];
}

// ---------------- GEMM1 compute (after staging) ----------------
__device__ __forceinline__ void gemm1_compute(int bx, int tid,
    const float* __restrict__ W, const float* __restrict__ bias,
    float* __restrict__ Y, float* __restrict__ part,
    float* xT, float* s1, float* s2){
  int r0 = bx*32;
  int tx = tid & 15, ty = tid >> 4;
  int c = tx*4, r = ty*2;
  float acc[2][4];
  #pragma unroll
  for (int i=0;i<2;i++){
    #pragma unroll
    for (int j=0;j<4;j++) acc[i][j] = 0.f;
  }
  for (int d=0; d<64; d++){
    float2 xv = *(const float2*)&xT[d*34 + r];
    float4 wv = *(const float4*)(W + d*64 + c);
    acc[0][0] = fmaf(xv.x, wv.x, acc[0][0]);
    acc[0][1] = fmaf(xv.x, wv.y, acc[0][1]);
    acc[0][2] = fmaf(xv.x, wv.z, acc[0][2]);
    acc[0][3] = fmaf(xv.x, wv.w, acc[0][3]);
    acc[1][0] = fmaf(xv.y, wv.x, acc[1][0]);
    acc[1][1] = fmaf(xv.y, wv.y, acc[1][1]);
    acc[1][2] = fmaf(xv.y, wv.z, acc[1][2]);
    acc[1][3] = fmaf(xv.y, wv.w, acc[1][3]);
  }
  float4 bz = *(const float4*)(bias + c);
  float bzv[4] = {bz.x, bz.y, bz.z, bz.w};
  float out0[4], out1[4];
  #pragma unroll
  for (int j=0;j<4;j++){
    out0[j] = acc[0][j] + bzv[j];
    out1[j] = acc[1][j] + bzv[j];
    s1[(c+j)*16+ty] = out0[j] + out1[j];
    s2[(c+j)*16+ty] = out0[j]*out0[j] + out1[j]*out1[j];
  }
  *(float4*)&Y[(size_t)(r0+r)*64 + c]   = make_float4(out0[0],out0[1],out0[2],out0[3]);
  *(float4*)&Y[(size_t)(r0+r+1)*64 + c] = make_float4(out1[0],out1[1],out1[2],out1[3]);
  __syncthreads();
  if (tid < 64){
    float sm=0.f, ss=0.f;
    #pragma unroll
    for (int q=0;q<16;q++){ sm += s1[tid*16+q]; ss += s2[tid*16+q]; }
    part[bx*128 + tid] = sm;
    part[bx*128 + 64 + tid] = ss;
  }
}

// ---------------- GEMM1 body (64->64) + stats, x0f input ----------------
__device__ __forceinline__ void gemm1_body(int bx, int tid,
    const float* __restrict__ X, const float* __restrict__ W,
    const float* __restrict__ bias, float* __restrict__ Y,
    float* __restrict__ part, float* xT, float* s1, float* s2){
  int r0 = bx*32;
  #pragma unroll
  for (int u=0; u<2; u++){
    float4 v = ((const float4*)(X + (size_t)r0*64))[u*256+tid];
    int fi = (u*256+tid)*4;
    int r = fi >> 6, d = fi & 63;
    xT[(d+0)*34 + r] = v.x;
    xT[(d+1)*34 + r] = v.y;
    xT[(d+2)*34 + r] = v.z;
    xT[(d+3)*34 + r] = v.w;
  }
  __syncthreads();
  gemm1_compute(bx, tid, W, bias, Y, part, xT, s1, s2);
}

__global__ void k_gemm1_stats(const float* __restrict__ X, const float* __restrict__ W,
                              const float* __restrict__ bias, float* __restrict__ Y,
                              float* __restrict__ part){
  __shared__ float xT[64*34];
  __shared__ float s1[1024], s2[1024];
  gemm1_body(blockIdx.x, threadIdx.x, X, W, bias, Y, part, xT, s1, s2);
}

__global__ void k_gemm1M(const float* __restrict__ X, const float* __restrict__ W1b,
                         const float* __restrict__ b1b, float* __restrict__ Y0,
                         float* __restrict__ Y1, float* __restrict__ part0,
                         float* __restrict__ part1){
  __shared__ float xT[64*34];
  __shared__ float s1[1024], s2[1024];
  int t  = blockIdx.x >> 8;
  int bx = blockIdx.x & 255;
  gemm1_body(bx, threadIdx.x, X, W1b + t*CCH*CCH, b1b + t*64,
             t ? Y1 : Y0, t ? part1 : part0, xT, s1, s2);
}

// gemm1 merged + transpose-fused: stages directly from x (B,C,N) with
// coalesced n-major float4 reads, and emits x0f (B,N,C) from the staged
// tile (t=0 instances only). Removes the k_transpose launch + 4MB read.
__global__ void k_gemm1MT(const float* __restrict__ x, const float* __restrict__ W1b,
                          const float* __restrict__ b1b, float* __restrict__ Y0,
                          float* __restrict__ Y1, float* __restrict__ part0,
                          float* __restrict__ part1, float* __restrict__ x0f){
  __shared__ float xT[64*34];
  __shared__ float s1[1024], s2[1024];
  int t  = blockIdx.x >> 8;
  int bx = blockIdx.x & 255;
  int tid = threadIdx.x;
  int r0 = bx*32;
  int b  = r0 >> 12;            /* NN=4096 rows per batch */
  int n0 = r0 & (NN-1);
  {
    int d = tid >> 3, f = tid & 7;   /* 64 d x 8 float4-slots = 512 loads... 256 thr -> 2 each */
    #pragma unroll
    for (int u=0; u<2; u++){
      int dd = d + u*32;
      float4 v = *(const float4*)(x + ((size_t)(b*CCH + dd))*NN + n0 + f*4);
      xT[dd*34 + f*4 + 0] = v.x;
      xT[dd*34 + f*4 + 1] = v.y;
      xT[dd*34 + f*4 + 2] = v.z;
      xT[dd*34 + f*4 + 3] = v.w;
    }
  }
  __syncthreads();
  /* emit x0f tile (read-only on xT, concurrent with compute) */
  if (t == 0){
    #pragma unroll
    for (int u=0; u<2; u++){
      int idx = u*256 + tid;        /* 512 float4 slots = 32 rows x 16 c4 */
      int lr  = idx >> 4;
      int c4  = (idx & 15) * 4;
      float4 w;
      w.x = xT[(c4+0)*34 + lr];
      w.y = xT[(c4+1)*34 + lr];
      w.z = xT[(c4+2)*34 + lr];
      w.w = xT[(c4+3)*34 + lr];
      *(float4*)&x0f[((size_t)(r0+lr))*64 + c4] = w;
    }
  }
  gemm1_compute(bx, tid, W1b + t*CCH*CCH, b1b + t*64,
                t ? Y1 : Y0, t ? part1 : part0, xT, s1, s2);
}

// ---------------- GEMM2 body (128->64) + stats ----------------
__device__ __forceinline__ void gemm2_body(int bx, int tid,
    const float* __restrict__ X, const float* __restrict__ W,
    const float* __restrict__ bias, float* __restrict__ Y,
    float* __restrict__ part, float* xT, float* s1, float* s2){
  int r0 = bx*32;
  #pragma unroll
  for (int u=0; u<4; u++){
    float4 v = ((const float4*)(X + (size_t)r0*128))[u*256+tid];
    int fi = (u*256+tid)*4;
    int r = fi >> 7, d = fi & 127;
    xT[(d+0)*34 + r] = v.x;
    xT[(d+1)*34 + r] = v.y;
    xT[(d+2)*34 + r] = v.z;
    xT[(d+3)*34 + r] = v.w;
  }
  __syncthreads();
  int tx = tid & 15, ty = tid >> 4;
  int c = tx*4, r = ty*2;
  float acc[2][4];
  #pragma unroll
  for (int i=0;i<2;i++){
    #pragma unroll
    for (int j=0;j<4;j++) acc[i][j] = 0.f;
  }
  for (int d=0; d<128; d++){
    float2 xv = *(const float2*)&xT[d*34 + r];
    float4 wv = *(const float4*)(W + d*64 + c);
    acc[0][0] = fmaf(xv.x, wv.x, acc[0][0]);
    acc[0][1] = fmaf(xv.x, wv.y, acc[0][1]);
    acc[0][2] = fmaf(xv.x, wv.z, acc[0][2]);
    acc[0][3] = fmaf(xv.x, wv.w, acc[0][3]);
    acc[1][0] = fmaf(xv.y, wv.x, acc[1][0]);
    acc[1][1] = fmaf(xv.y, wv.y, acc[1][1]);
    acc[1][2] = fmaf(xv.y, wv.z, acc[1][2]);
    acc[1][3] = fmaf(xv.y, wv.w, acc[1][3]);
  }
  float4 bz = *(const float4*)(bias + c);
  float bzv[4] = {bz.x, bz.y, bz.z, bz.w};
  float out0[4], out1[4];
  #pragma unroll
  for (int j=0;j<4;j++){
    out0[j] = acc[0][j] + bzv[j];
    out1[j] = acc[1][j] + bzv[j];
    s1[(c+j)*16+ty] = out0[j] + out1[j];
    s2[(c+j)*16+ty] = out0[j]*out0[j] + out1[j]*out1[j];
  }
  *(float4*)&Y[(size_t)(r0+r)*64 + c]   = make_float4(out0[0],out0[1],out0[2],out0[3]);
  *(float4*)&Y[(size_t)(r0+r+1)*64 + c] = make_float4(out1[0],out1[1],out1[2],out1[3]);
  __syncthreads();
  if (tid < 64){
    float sm=0.f, ss=0.f;
    #pragma unroll
    for (int q=0;q<16;q++){ sm += s1[tid*16+q]; ss += s2[tid*16+q]; }
    part[bx*128 + tid] = sm;
    part[bx*128 + 64 + tid] = ss;
  }
}

__global__ void k_gemm2_stats(const float* __restrict__ X, const float* __restrict__ W,
                              const float* __restrict__ bias, float* __restrict__ Y,
                              float* __restrict__ part){
  __shared__ float xT[128*34];
  __shared__ float s1[1024], s2[1024];
  gemm2_body(blockIdx.x, threadIdx.x, X, W, bias, Y, part, xT, s1, s2);
}

__global__ void k_gemm2M(const float* __restrict__ X0, const float* __restrict__ X1,
                         const float* __restrict__ W2b, const float* __restrict__ b2b,
                         float* __restrict__ Y0, float* __restrict__ Y1,
                         float* __restrict__ part0, float* __restrict__ part1){
  __shared__ float xT[128*34];
  __shared__ float s1[1024], s2[1024];
  int t  = blockIdx.x >> 8;
  int bx = blockIdx.x & 255;
  gemm2_body(bx, threadIdx.x, t ? X1 : X0, W2b + t*C2*CCH, b2b + t*64,
             t ? Y1 : Y0, t ? part1 : part0, xT, s1, s2);
}

// ---------------- applynorm body ----------------
__device__ __forceinline__ void applynorm_body(int bx, int tid,
    float* __restrict__ h, const float* __restrict__ part,
    const float* __restrict__ g, const float* __restrict__ bt,
    float* __restrict__ xn, float* __restrict__ sq,
    float* scshL, float* s1, float* s2){
  {
    int c = tid & 63, sl = tid >> 6;
    float sm=0.f, ss=0.f;
    #pragma unroll 4
    for (int u=sl*64; u<sl*64+64; u++){ sm += part[u*128+c]; ss += part[u*128+64+c]; }
    s1[tid]=sm; s2[tid]=ss;
  }
  __syncthreads();
  if (tid < 64){
    float sm = s1[tid]+s1[64+tid]+s1[128+tid]+s1[192+tid];
    float ss = s2[tid]+s2[64+tid]+s2[128+tid]+s2[192+tid];
    float mean = sm/(float)R1;
    float var = fmaxf(ss/(float)R1 - mean*mean, 0.f);
    float sc = g[tid]*rsqrtf(var+1e-5f);
    scshL[tid] = sc; scshL[64+tid] = bt[tid] - mean*sc;
  }
  __syncthreads();
  int lane = tid & 63, w = tid >> 6;
  int r0 = bx*32;
  for (int it=0; it<8; it++){
    int r = r0 + w*8 + it;
    float v = fmaf(h[(size_t)r*64+lane], scshL[lane], scshL[64+lane]);
    h[(size_t)r*64+lane] = v;
    float s2v = v*v;
    #pragma unroll
    for (int off=32; off; off>>=1) s2v += __shfl_xor(s2v, off, 64);
    float den = fmaxf(sqrtf(s2v), 1e-12f);
    float xv = v/den;
    xn[(size_t)r*64+lane] = xv;
    float t2 = xv*xv;
    #pragma unroll
    for (int off=32; off; off>>=1) t2 += __shfl_xor(t2, off, 64);
    if (lane==0) sq[r] = t2;
  }
}

__global__ void k_applynorm3(float* __restrict__ h, const float* __restrict__ part,
                             const float* __restrict__ g, const float* __restrict__ bt,
                             float* __restrict__ xn, float* __restrict__ sq){
  __shared__ float scshL[128];
  __shared__ float s1[256], s2[256];
  applynorm_body(blockIdx.x, threadIdx.x, h, part, g, bt, xn, sq, scshL, s1, s2);
}

__global__ void k_applynormM(float* __restrict__ h0, float* __restrict__ h1,
                             const float* __restrict__ part0, const float* __restrict__ part1,
                             const float* __restrict__ g1b, const float* __restrict__ bt1b,
                             float* __restrict__ xn0, float* __restrict__ xn1,
                             float* __restrict__ sq0, float* __restrict__ sq1){
  __shared__ float scshL[128];
  __shared__ float s1[256], s2[256];
  int t  = blockIdx.x >> 8;
  int bx = blockIdx.x & 255;
  applynorm_body(bx, threadIdx.x, t ? h1 : h0, t ? part1 : part0,
                 g1b + t*64, bt1b + t*64, t ? xn1 : xn0, t ? sq1 : sq0,
                 scshL, s1, s2);
}

// ---------------- top-9 insert on packed u64 keys, branchless ----------------
__device__ __forceinline__ void topk_insert9u(unsigned long long key,
                                              unsigned long long* bk){
  bool c0 = key < bk[0], c1 = key < bk[1], c2 = key < bk[2], c3 = key < bk[3];
  bool c4 = key < bk[4], c5 = key < bk[5], c6 = key < bk[6], c7 = key < bk[7];
  bool c8 = key < bk[8];
  bk[8] = c7 ? bk[7] : (c8 ? key : bk[8]);
  bk[7] = c6 ? bk[6] : (c7 ? key : bk[7]);
  bk[6] = c5 ? bk[5] : (c6 ? key : bk[6]);
  bk[5] = c4 ? bk[4] : (c5 ? key : bk[5]);
  bk[4] = c3 ? bk[3] : (c4 ? key : bk[4]);
  bk[3] = c2 ? bk[2] : (c3 ? key : bk[3]);
  bk[2] = c1 ? bk[1] : (c2 ? key : bk[2]);
  bk[1] = c0 ? bk[0] : (c1 ? key : bk[1]);
  bk[0] = c0 ? key : bk[0];
}

// -------- KNN body (r8 config, floor ~120us/t) --------
__device__ __forceinline__ void knn_body(int bx, int tid,
                                         const float* __restrict__ xn,
                                         const float* __restrict__ sq,
                                         float* __restrict__ pd, int* __restrict__ pi_,
                                         float* xjL, float* sqL){
  int b     = bx >> 7;
  int ib    = (bx >> 4) & 7;
  int split = bx & 15;
  int half = tid >> 8;
  int li   = tid & 255;
  const float* xb = xn + (size_t)b*NN*64;
  const float* sqb = sq + (size_t)b*NN;
  int i0 = ib*512 + li;
  int i1 = i0 + 256;
  f32x4 xi0[16], xi1[16];
  {
    const f32x4* p0 = (const f32x4*)(xb + (size_t)i0*64);
    const f32x4* p1 = (const f32x4*)(xb + (size_t)i1*64);
    #pragma unroll
    for (int q=0;q<16;q++){ xi0[q] = p0[q]; xi1[q] = p1[q]; }
  }
  float sqi0 = sqb[i0], sqi1 = sqb[i1];
  unsigned long long bk0[9], bk1[9];
  #pragma unroll
  for (int q=0;q<9;q++){ bk0[q] = 0xFFFFFFFFFFFFFFFFull; bk1[q] = 0xFFFFFFFFFFFFFFFFull; }
  int jbase = split*CHUNK;
  {
    const float4* src = (const float4*)(xb + (size_t)jbase*64);
    float4* dst = (float4*)xjL;
    #pragma unroll
    for (int u=0; u<8; u++) dst[u*512 + tid] = src[u*512 + tid];
    if (tid < CHUNK) sqL[tid] = sq ? sqb[jbase + tid] : 0.f;
  }
  __syncthreads();
  int jl0 = half*128;
  #pragma unroll 1
  for (int jj=0; jj<128; jj++){
    int jl = jl0 + jj;
    const f32x4* xj4 = (const f32x4*)(xjL + jl*64);
    f32x2 a01_0 = {0.f, 0.f}, a23_0 = {0.f, 0.f};
    f32x2 a01_1 = {0.f, 0.f}, a23_1 = {0.f, 0.f};
    #pragma unroll
    for (int q=0;q<16;q++){
      f32x4 v = xj4[q];
      f32x2 vlo = __builtin_shufflevector(v, v, 0, 1);
      f32x2 vhi = __builtin_shufflevector(v, v, 2, 3);
      a01_0 = __builtin_elementwise_fma(__builtin_shufflevector(xi0[q], xi0[q], 0, 1), vlo, a01_0);
      a23_0 = __builtin_elementwise_fma(__builtin_shufflevector(xi0[q], xi0[q], 2, 3), vhi, a23_0);
      a01_1 = __builtin_elementwise_fma(__builtin_shufflevector(xi1[q], xi1[q], 0, 1), vlo, a01_1);
      a23_1 = __builtin_elementwise_fma(__builtin_shufflevector(xi1[q], xi1[q], 2, 3), vhi, a23_1);
    }
    float sqj = sqL[jl];
    int j = jbase + jl;
    float dot0 = (a01_0.x + a01_0.y) + (a23_0.x + a23_0.y);
    float dot1 = (a01_1.x + a01_1.y) + (a23_1.x + a23_1.y);
    float d0 = fmaxf(sqi0 + sqj - 2.f*dot0, 0.f);
    float d1 = fmaxf(sqi1 + sqj - 2.f*dot1, 0.f);
    unsigned long long key0 = ((unsigned long long)__float_as_uint(d0) << 32)
                            | (unsigned)j;
    unsigned long long key1 = ((unsigned long long)__float_as_uint(d1) << 32)
                            | (unsigned)j;
    topk_insert9u(key0, bk0);
    topk_insert9u(key1, bk1);
  }
  __syncthreads();
  unsigned long long* mL = (unsigned long long*)xjL;
  if (half == 1){
    #pragma unroll
    for (int q=0;q<9;q++){
      mL[(size_t)(li*2+0)*9+q] = bk0[q];
      mL[(size_t)(li*2+1)*9+q] = bk1[q];
    }
  }
  __syncthreads();
  if (half == 0){
    #pragma unroll
    for (int q=0;q<9;q++) topk_insert9u(mL[(size_t)(li*2+0)*9+q], bk0);
    #pragma unroll
    for (int q=0;q<9;q++) topk_insert9u(mL[(size_t)(li*2+1)*9+q], bk1);
    size_t base0 = (((size_t)(b*NN + i0))*SPLIT + split)*9;
    size_t base1 = (((size_t)(b*NN + i1))*SPLIT + split)*9;
    #pragma unroll
    for (int q=0;q<9;q++){
      pd[base0+q] = __uint_as_float((unsigned)(bk0[q] >> 32));
      pi_[base0+q] = (int)(unsigned)(bk0[q] & 0xFFFFFFFFull);
      pd[base1+q] = __uint_as_float((unsigned)(bk1[q] >> 32));
      pi_[base1+q] = (int)(unsigned)(bk1[q] & 0xFFFFFFFFull);
    }
  }
}

__global__ __launch_bounds__(512) __attribute__((amdgpu_waves_per_eu(2, 2)))
void k_knn(const float* __restrict__ xn,
           const float* __restrict__ sq,
           float* __restrict__ pd, int* __restrict__ pi_){
  __shared__ __align__(16) float xjL[CHUNK*64];   /* 64 KB */
  __shared__ float sqL[CHUNK];
  knn_body(blockIdx.x, threadIdx.x, xn, sq, pd, pi_, xjL, sqL);
}

// t-looped knn: kept for reference; measured +6us vs split launches (r17).
__global__ __launch_bounds__(512) __attribute__((amdgpu_waves_per_eu(2, 2)))
void k_knn2(const float* __restrict__ xn0, const float* __restrict__ xn1,
            const float* __restrict__ sq0, const float* __restrict__ sq1,
            float* __restrict__ pd0, float* __restrict__ pd1,
            int* __restrict__ pi0, int* __restrict__ pi1){
  __shared__ __align__(16) float xjL[CHUNK*64];   /* 64 KB */
  __shared__ float sqL[CHUNK];
  knn_body(blockIdx.x, threadIdx.x, xn0, sq0, pd0, pi0, xjL, sqL);
  __syncthreads();
  knn_body(blockIdx.x, threadIdx.x, xn1, sq1, pd1, pi1, xjL, sqL);
}

// ---------------- edge1 body: fused merge + edge-GEMM stats (+Yg store) ----------
__device__ __forceinline__ void edge1_body(int bx, int tid,
    const float* __restrict__ h, const float* __restrict__ pd,
    const int* __restrict__ pi_, const float* __restrict__ Wg,
    const float* __restrict__ bg, int* __restrict__ idxf,
    float* __restrict__ part, float* __restrict__ Yg, int storeYg,
    float* dxAll, float* xiAll, float* sSum, float* sSq){
  int lane = tid & 63, wv = tid >> 6;
  float* dxW = dxAll + wv*576;
  float* xiW = xiAll + wv*64;
  int c0 = lane, c1 = lane + 64;
  float bias0 = bg[c0], bias1 = bg[c1];
  float sm0=0.f, ss0=0.f, sm1=0.f, ss1=0.f;
  for (int u4=0; u4<4; u4++){
    int node = bx*16 + wv*4 + u4;
    int b = node >> 12;
    size_t cb = (size_t)node*(SPLIT*9);
    float d0 = pd[cb+lane], d1 = pd[cb+64+lane], d2 = INFINITY;
    int   j0 = pi_[cb+lane], j1 = pi_[cb+64+lane], j2 = 0x7fffffff;
    if (lane < 16){ d2 = pd[cb+128+lane]; j2 = pi_[cb+128+lane]; }
    int kidx[9];
    #pragma unroll
    for (int s=0; s<9; s++){
      float ld = d0; int lj = j0;
      if (d1 < ld || (d1 == ld && j1 < lj)){ ld = d1; lj = j1; }
      if (d2 < ld || (d2 == ld && j2 < lj)){ ld = d2; lj = j2; }
      #pragma unroll
      for (int off=1; off<64; off<<=1){
        float od = __shfl_xor(ld, off, 64);
        int   oj = __shfl_xor(lj, off, 64);
        if (od < ld || (od == ld && oj < lj)){ ld = od; lj = oj; }
      }
      kidx[s] = lj & (NN-1);
      if (lane == 0) idxf[(size_t)node*9 + s] = lj & (NN-1);
      if (j0 == lj){ d0 = INFINITY; j0 = 0x7fffffff; }
      if (j1 == lj){ d1 = INFINITY; j1 = 0x7fffffff; }
      if (j2 == lj){ d2 = INFINITY; j2 = 0x7fffffff; }
    }
    float xi_l = h[(size_t)node*64 + lane];
    xiW[lane] = xi_l;
    #pragma unroll
    for (int k=0; k<9; k++)
      dxW[k*64+lane] = h[((size_t)(b*NN + kidx[k]))*64 + lane] - xi_l;
    float common0 = bias0, common1 = bias1;
    const float4* xi4 = (const float4*)xiW;
    #pragma unroll 4
    for (int d4=0; d4<16; d4++){
      float4 xv = xi4[d4];
      int d = d4*4;
      common0 = fmaf(xv.x, Wg[(d+0)*C2+c0], common0);
      common0 = fmaf(xv.y, Wg[(d+1)*C2+c0], common0);
      common0 = fmaf(xv.z, Wg[(d+2)*C2+c0], common0);
      common0 = fmaf(xv.w, Wg[(d+3)*C2+c0], common0);
      common1 = fmaf(xv.x, Wg[(d+0)*C2+c1], common1);
      common1 = fmaf(xv.y, Wg[(d+1)*C2+c1], common1);
      common1 = fmaf(xv.z, Wg[(d+2)*C2+c1], common1);
      common1 = fmaf(xv.w, Wg[(d+3)*C2+c1], common1);
    }
    float a0[9], a1[9];
    #pragma unroll
    for (int k=0;k<9;k++){ a0[k]=0.f; a1[k]=0.f; }
    const float4* dx4 = (const float4*)dxW;
    for (int d4=0; d4<16; d4++){
      int d = d4*4;
      float w0v[4], w1v[4];
      #pragma unroll
      for (int i=0;i<4;i++){
        w0v[i] = Wg[(64+d+i)*C2+c0];
        w1v[i] = Wg[(64+d+i)*C2+c1];
      }
      #pragma unroll
      for (int k=0;k<9;k++){
        float4 dx = dx4[k*16+d4];
        a0[k] = fmaf(dx.x, w0v[0], a0[k]);
        a0[k] = fmaf(dx.y, w0v[1], a0[k]);
        a0[k] = fmaf(dx.z, w0v[2], a0[k]);
        a0[k] = fmaf(dx.w, w0v[3], a0[k]);
        a1[k] = fmaf(dx.x, w1v[0], a1[k]);
        a1[k] = fmaf(dx.y, w1v[1], a1[k]);
        a1[k] = fmaf(dx.z, w1v[2], a1[k]);
        a1[k] = fmaf(dx.w, w1v[3], a1[k]);
      }
    }
    #pragma unroll
    for (int k=0;k<9;k++){
      float v0 = common0 + a0[k], v1 = common1 + a1[k];
      sm0 += v0; ss0 += v0*v0; sm1 += v1; ss1 += v1*v1;
      if (storeYg){
        size_t yb = ((size_t)node*9 + k)*C2;
        Yg[yb + c0] = v0;
        Yg[yb + c1] = v1;
      }
    }
  }
  sSum[wv*128+lane] = sm0; sSum[wv*128+64+lane] = sm1;
  sSq [wv*128+lane] = ss0; sSq [wv*128+64+lane] = ss1;
  __syncthreads();
  if (tid < 128){
    float sm = sSum[tid]+sSum[128+tid]+sSum[256+tid]+sSum[384+tid];
    float ss = sSq[tid]+sSq[128+tid]+sSq[256+tid]+sSq[384+tid];
    part[bx*256 + tid] = sm;
    part[bx*256 + 128 + tid] = ss;
  }
}

__global__ __launch_bounds__(256) void k_edge1(const float* __restrict__ h,
                        const float* __restrict__ pd, const int* __restrict__ pi_,
                        const float* __restrict__ Wg, const float* __restrict__ bg,
                        int* __restrict__ idxf, float* __restrict__ part,
                        float* __restrict__ Yg, int storeYg){
  __shared__ float dxAll[4*576];
  __shared__ float xiAll[4*64];
  __shared__ float sSum[512], sSq[512];
  edge1_body(blockIdx.x, threadIdx.x, h, pd, pi_, Wg, bg, idxf, part, Yg, storeYg,
             dxAll, xiAll, sSum, sSq);
}

__global__ __launch_bounds__(256) void k_edge1M(
    const float* __restrict__ h0, const float* __restrict__ h1,
    const float* __restrict__ pd0, const float* __restrict__ pd1,
    const int* __restrict__ pi0, const int* __restrict__ pi1,
    const float* __restrict__ Wgb, const float* __restrict__ bgb,
    int* __restrict__ idxf0, int* __restrict__ idxf1,
    float* __restrict__ part0, float* __restrict__ part1,
    float* __restrict__ Yg0, float* __restrict__ Yg1){
  __shared__ float dxAll[4*576];
  __shared__ float xiAll[4*64];
  __shared__ float sSum[512], sSq[512];
  int t  = blockIdx.x >> 9;
  int bx = blockIdx.x & 511;
  edge1_body(bx, threadIdx.x, t ? h1 : h0, t ? pd1 : pd0, t ? pi1 : pi0,
             Wgb + t*C2*C2, bgb + t*C2, t ? idxf1 : idxf0,
             t ? part1 : part0, t ? Yg1 : Yg0, 1,
             dxAll, xiAll, sSum, sSq);
}

// ---------------- edge2m body: inline fin + BN + gelu + max over Yg ---------------
__device__ __forceinline__ void edge2m_body(int bx, int tid,
    const float* __restrict__ Yg, const float* __restrict__ part,
    const float* __restrict__ gg, const float* __restrict__ btg,
    float* __restrict__ gmax, float* scshL, float* s1, float* s2){
  {
    int cc = tid & 127, sl = tid >> 7;
    float sm=0.f, ss=0.f;
    #pragma unroll 4
    for (int u=sl*256; u<sl*256+256; u++){ sm += part[u*256+cc]; ss += part[u*256+128+cc]; }
    s1[tid]=sm; s2[tid]=ss;
  }
  __syncthreads();
  if (tid < 128){
    float sm = s1[tid]+s1[128+tid];
    float ss = s2[tid]+s2[128+tid];
    float mean = sm/(float)RG;
    float var = fmaxf(ss/(float)RG - mean*mean, 0.f);
    float sc = gg[tid]*rsqrtf(var+1e-5f);
    scshL[tid] = sc; scshL[128+tid] = btg[tid] - mean*sc;
  }
  __syncthreads();
  size_t base = (size_t)bx*2048;
  for (int p=0; p<8; p++){
    size_t idx = base + p*256 + tid;
    int c = idx & 127;
    size_t node = idx >> 7;
    float sc = scshL[c], sh = scshL[128+c];
    size_t yb = node*9*C2 + c;
    float m = -INFINITY;
    #pragma unroll
    for (int k=0;k<9;k++){
      m = fmaxf(m, gelu(fmaf(Yg[yb + (size_t)k*C2], sc, sh)));
    }
    gmax[idx] = m;
  }
}

__global__ __launch_bounds__(256) void k_edge2m(const float* __restrict__ Yg,
                        const float* __restrict__ part, const float* __restrict__ gg,
                        const float* __restrict__ btg, float* __restrict__ gmax){
  __shared__ float scshL[256];
  __shared__ float s1[256], s2[256];
  edge2m_body(blockIdx.x, threadIdx.x, Yg, part, gg, btg, gmax, scshL, s1, s2);
}

__global__ __launch_bounds__(256) void k_edge2mM(
    const float* __restrict__ Yg0, const float* __restrict__ Yg1,
    const float* __restrict__ part0, const float* __restrict__ part1,
    const float* __restrict__ ggb, const float* __restrict__ btgb,
    float* __restrict__ gmax0, float* __restrict__ gmax1){
  __shared__ float scshL[256];
  __shared__ float s1[256], s2[256];
  int t  = blockIdx.x >> 9;
  int bx = blockIdx.x & 511;
  edge2m_body(bx, threadIdx.x, t ? Yg1 : Yg0, t ? part1 : part0,
              ggb + t*C2, btgb + t*C2, t ? gmax1 : gmax0, scshL, s1, s2);
}

// ------- edge pass 2 (fallback): inline fin + recompute + BN + gelu + max ---------
__global__ __launch_bounds__(256) void k_edge2(const float* __restrict__ h,
                        const int* __restrict__ idxf,
                        const float* __restrict__ Wg, const float* __restrict__ bg,
                        const float* __restrict__ part, const float* __restrict__ gg,
                        const float* __restrict__ btg, float* __restrict__ gmax){
  __shared__ float dxAll[4*576];
  __shared__ float xiAll[4*64];
  __shared__ float scshL[256];
  __shared__ float s1[256], s2[256];
  int tid = threadIdx.x, lane = tid & 63, wv = tid >> 6;
  {
    int cc = tid & 127, sl = tid >> 7;
    float sm=0.f, ss=0.f;
    #pragma unroll 4
    for (int u=sl*256; u<sl*256+256; u++){ sm += part[u*256+cc]; ss += part[u*256+128+cc]; }
    s1[tid]=sm; s2[tid]=ss;
  }
  __syncthreads();
  if (tid < 128){
    float sm = s1[tid]+s1[128+tid];
    float ss = s2[tid]+s2[128+tid];
    float mean = sm/(float)RG;
    float var = fmaxf(ss/(float)RG - mean*mean, 0.f);
    float sc = gg[tid]*rsqrtf(var+1e-5f);
    scshL[tid] = sc; scshL[128+tid] = btg[tid] - mean*sc;
  }
  __syncthreads();
  float* dxW = dxAll + wv*576;
  float* xiW = xiAll + wv*64;
  int c0 = lane, c1 = lane + 64;
  float bias0 = bg[c0], bias1 = bg[c1];
  float sc0 = scshL[c0], sh0 = scshL[128+c0];
  float sc1 = scshL[c1], sh1 = scshL[128+c1];
  for (int u4=0; u4<4; u4++){
    int node = blockIdx.x*16 + wv*4 + u4;
    int b = node >> 12;
    int kidx[9];
    #pragma unroll
    for (int k=0;k<9;k++) kidx[k] = idxf[(size_t)node*9 + k] & (NN-1);
    float xi_l = h[(size_t)node*64 + lane];
    xiW[lane] = xi_l;
    #pragma unroll
    for (int k=0; k<9; k++)
      dxW[k*64+lane] = h[((size_t)(b*NN + kidx[k]))*64 + lane] - xi_l;
    float common0 = bias0, common1 = bias1;
    for (int d=0; d<64; d++){
      float xv = xiW[d];
      common0 = fmaf(xv, Wg[d*C2+c0], common0);
      common1 = fmaf(xv, Wg[d*C2+c1], common1);
    }
    float a0[9], a1[9];
    #pragma unroll
    for (int k=0;k<9;k++){ a0[k]=0.f; a1[k]=0.f; }
    for (int d=0; d<64; d++){
      float w0 = Wg[(64+d)*C2+c0], w1 = Wg[(64+d)*C2+c1];
      #pragma unroll
      for (int k=0;k<9;k++){
        float dxv = dxW[k*64+d];
        a0[k] = fmaf(dxv, w0, a0[k]);
        a1[k] = fmaf(dxv, w1, a1[k]);
      }
    }
    float m0 = -INFINITY, m1 = -INFINITY;
    #pragma unroll
    for (int k=0;k<9;k++){
      m0 = fmaxf(m0, gelu(fmaf(common0 + a0[k], sc0, sh0)));
      m1 = fmaxf(m1, gelu(fmaf(common1 + a1[k], sc1, sh1)));
    }
    gmax[(size_t)node*C2 + c0] = m0;
    gmax[(size_t)node*C2 + c1] = m1;
  }
}

// ---------------- FFN1 body ----------------
__device__ __forceinline__ void ffn1_body(int bx, int tid,
    const float* __restrict__ Y2, const float* __restrict__ part,
    const float* __restrict__ g2, const float* __restrict__ bt2,
    const float* __restrict__ x0f, float* __restrict__ outt,
    const float* __restrict__ Wf1, const float* __restrict__ bf1,
    float* __restrict__ partB, float* scshL, float* otT, float* s1, float* s2){
  int r0 = bx*32;
  {
    int c = tid & 63, sl = tid >> 6;
    float sm=0.f, ss=0.f;
    #pragma unroll 4
    for (int u=sl*64; u<sl*64+64; u++){ sm += part[u*128+c]; ss += part[u*128+64+c]; }
    s1[tid]=sm; s2[tid]=ss;
  }
  __syncthreads();
  if (tid < 64){
    float sm = s1[tid]+s1[64+tid]+s1[128+tid]+s1[192+tid];
    float ss = s2[tid]+s2[64+tid]+s2[128+tid]+s2[192+tid];
    float mean = sm/(float)R1;
    float var = fmaxf(ss/(float)R1 - mean*mean, 0.f);
    float sc = g2[tid]*rsqrtf(var+1e-5f);
    scshL[tid] = sc; scshL[64+tid] = bt2[tid] - mean*sc;
  }
  __syncthreads();
  #pragma unroll
  for (int p=0; p<8; p++){
    int idx = p*256 + tid;
    int lr = idx >> 6, cc = idx & 63;
    size_t gi = (size_t)(r0+lr)*64 + cc;
    float v = fmaf(Y2[gi], scshL[cc], scshL[64+cc]) + x0f[gi];
    otT[cc*36 + lr] = v;
    outt[gi] = v;
  }
  __syncthreads();
  int tx = tid & 63, ty = tid >> 6;
  int c = tx*4, r = ty*8;
  float acc[8][4];
  #pragma unroll
  for (int i=0;i<8;i++){
    #pragma unroll
    for (int j=0;j<4;j++) acc[i][j]=0.f;
  }
  for (int d=0; d<64; d++){
    float4 xa = *(const float4*)&otT[d*36 + r];
    float4 xb = *(const float4*)&otT[d*36 + r + 4];
    float4 wv = *(const float4*)(Wf1 + d*256 + c);
    float xs[8] = {xa.x,xa.y,xa.z,xa.w, xb.x,xb.y,xb.z,xb.w};
    #pragma unroll
    for (int i=0;i<8;i++){
      acc[i][0] = fmaf(xs[i], wv.x, acc[i][0]);
      acc[i][1] = fmaf(xs[i], wv.y, acc[i][1]);
      acc[i][2] = fmaf(xs[i], wv.z, acc[i][2]);
      acc[i][3] = fmaf(xs[i], wv.w, acc[i][3]);
    }
  }
  float4 bz = *(const float4*)(bf1 + c);
  float bzv[4] = {bz.x, bz.y, bz.z, bz.w};
  #pragma unroll
  for (int j=0;j<4;j++){
    float cs=0.f, cq=0.f;
    #pragma unroll
    for (int i=0;i<8;i++){
      float v = acc[i][j] + bzv[j];
      cs += v; cq += v*v;
    }
    s1[(c+j)*4 + ty] = cs;
    s2[(c+j)*4 + ty] = cq;
  }
  __syncthreads();
  {
    float sm = s1[tid*4]+s1[tid*4+1]+s1[tid*4+2]+s1[tid*4+3];
    float ss = s2[tid*4]+s2[tid*4+1]+s2[tid*4+2]+s2[tid*4+3];
    partB[bx*512 + tid] = sm;
    partB[bx*512 + 256 + tid] = ss;
  }
}

__global__ void k_ffn1_fused(const float* __restrict__ Y2, const float* __restrict__ part,
                             const float* __restrict__ g2, const float* __restrict__ bt2,
                             const float* __restrict__ x0f, float* __restrict__ outt,
                             const float* __restrict__ Wf1, const float* __restrict__ bf1,
                             float* __restrict__ partB){
  __shared__ float scshL[128];
  __shared__ float otT[64*36];
  __shared__ float s1[1024], s2[1024];
  ffn1_body(blockIdx.x, threadIdx.x, Y2, part, g2, bt2, x0f, outt, Wf1, bf1,
            partB, scshL, otT, s1, s2);
}

__global__ void k_ffn1M(const float* __restrict__ Y2_0, const float* __restrict__ Y2_1,
                        const float* __restrict__ part0, const float* __restrict__ part1,
                        const float* __restrict__ g2b, const float* __restrict__ bt2b,
                        const float* __restrict__ x0f,
                        float* __restrict__ outt0, float* __restrict__ outt1,
                        const float* __restrict__ Wf1b, const float* __restrict__ bf1b,
                        float* __restrict__ partB0, float* __restrict__ partB1){
  __shared__ float scshL[128];
  __shared__ float otT[64*36];
  __shared__ float s1[1024], s2[1024];
  int t  = blockIdx.x >> 8;
  int bx = blockIdx.x & 255;
  ffn1_body(bx, threadIdx.x, t ? Y2_1 : Y2_0, t ? part1 : part0,
            g2b + t*64, bt2b + t*64, x0f, t ? outt1 : outt0,
            Wf1b + t*CCH*C4, bf1b + t*C4, t ? partB1 : partB0,
            scshL, otT, s1, s2);
}

// ---------------- FFN2 body ----------------
__device__ __forceinline__ void ffn2_body(int bx, int tid,
    const float* __restrict__ outt, const float* __restrict__ Wf1,
    const float* __restrict__ bf1, const float* __restrict__ partB,
    const float* __restrict__ gf1, const float* __restrict__ btf1,
    const float* __restrict__ Wf2, const float* __restrict__ bf2,
    float* __restrict__ Yf2, float* __restrict__ partA,
    float* scshL, float* otT, float* fT, float* s1, float* s2){
  int r0 = bx*32;
  {
    float sm=0.f, ss=0.f;
    #pragma unroll 4
    for (int u=0; u<256; u++){ sm += partB[u*512+tid]; ss += partB[u*512+256+tid]; }
    float mean = sm/(float)R1;
    float var = fmaxf(ss/(float)R1 - mean*mean, 0.f);
    float sc = gf1[tid]*rsqrtf(var+1e-5f);
    scshL[tid] = sc; scshL[256+tid] = btf1[tid] - mean*sc;
  }
  #pragma unroll
  for (int p=0; p<8; p++){
    int idx = p*256 + tid;
    int lr = idx >> 6, cc = idx & 63;
    otT[cc*36 + lr] = outt[(size_t)r0*64 + idx];
  }
  __syncthreads();
  int tx = tid & 63, ty = tid >> 6;
  int c = tx*4, r = ty*8;
  {
    float acc[8][4];
    #pragma unroll
    for (int i=0;i<8;i++){
      #pragma unroll
      for (int j=0;j<4;j++) acc[i][j]=0.f;
    }
    for (int d=0; d<64; d++){
      float4 xa = *(const float4*)&otT[d*36 + r];
      float4 xb = *(const float4*)&otT[d*36 + r + 4];
      float4 wv = *(const float4*)(Wf1 + d*256 + c);
      float xs[8] = {xa.x,xa.y,xa.z,xa.w, xb.x,xb.y,xb.z,xb.w};
      #pragma unroll
      for (int i=0;i<8;i++){
        acc[i][0] = fmaf(xs[i], wv.x, acc[i][0]);
        acc[i][1] = fmaf(xs[i], wv.y, acc[i][1]);
        acc[i][2] = fmaf(xs[i], wv.z, acc[i][2]);
        acc[i][3] = fmaf(xs[i], wv.w, acc[i][3]);
      }
    }
    float4 bz = *(const float4*)(bf1 + c);
    float bzv[4] = {bz.x, bz.y, bz.z, bz.w};
    #pragma unroll
    for (int j=0;j<4;j++){
      float sc = scshL[c+j], sh = scshL[256+c+j];
      #pragma unroll
      for (int i=0;i<8;i++){
        float v = gelu(fmaf(acc[i][j] + bzv[j], sc, sh));
        fT[(c+j)*36 + r + i] = v;
      }
    }
  }
  __syncthreads();
  int tx2 = tid & 15, ty2 = tid >> 4;
  int c2 = tx2*4, r2 = ty2*2;
  float acc2[2][4];
  #pragma unroll
  for (int i=0;i<2;i++){
    #pragma unroll
    for (int j=0;j<4;j++) acc2[i][j]=0.f;
  }
  for (int d=0; d<256; d++){
    float2 xv = *(const float2*)&fT[d*36 + r2];
    float4 wv = *(const float4*)(Wf2 + d*64 + c2);
    acc2[0][0] = fmaf(xv.x, wv.x, acc2[0][0]);
    acc2[0][1] = fmaf(xv.x, wv.y, acc2[0][1]);
    acc2[0][2] = fmaf(xv.x, wv.z, acc2[0][2]);
    acc2[0][3] = fmaf(xv.x, wv.w, acc2[0][3]);
    acc2[1][0] = fmaf(xv.y, wv.x, acc2[1][0]);
    acc2[1][1] = fmaf(xv.y, wv.y, acc2[1][1]);
    acc2[1][2] = fmaf(xv.y, wv.z, acc2[1][2]);
    acc2[1][3] = fmaf(xv.y, wv.w, acc2[1][3]);
  }
  float4 b2 = *(const float4*)(bf2 + c2);
  float b2v[4] = {b2.x, b2.y, b2.z, b2.w};
  float out0[4], out1[4];
  #pragma unroll
  for (int j=0;j<4;j++){
    out0[j] = acc2[0][j] + b2v[j];
    out1[j] = acc2[1][j] + b2v[j];
    s1[(c2+j)*16 + ty2] = out0[j] + out1[j];
    s2[(c2+j)*16 + ty2] = out0[j]*out0[j] + out1[j]*out1[j];
  }
  *(float4*)&Yf2[(size_t)(r0+r2)*64 + c2]   = make_float4(out0[0],out0[1],out0[2],out0[3]);
  *(float4*)&Yf2[(size_t)(r0+r2+1)*64 + c2] = make_float4(out1[0],out1[1],out1[2],out1[3]);
  __syncthreads();
  if (tid < 64){
    float sm=0.f, ss=0.f;
    #pragma unroll
    for (int q=0;q<16;q++){ sm += s1[tid*16+q]; ss += s2[tid*16+q]; }
    partA[bx*128 + tid] = sm;
    partA[bx*128 + 64 + tid] = ss;
  }
}

__global__ void k_ffn2_fused(const float* __restrict__ outt, const float* __restrict__ Wf1,
                             const float* __restrict__ bf1, const float* __restrict__ partB,
                             const float* __restrict__ gf1, const float* __restrict__ btf1,
                             const float* __restrict__ Wf2, const float* __restrict__ bf2,
                             float* __restrict__ Yf2, float* __restrict__ partA){
  __shared__ float scshL[512];
  __shared__ float otT[64*36];
  __shared__ float fT[256*36];
  __shared__ float s1[1024], s2[1024];
  ffn2_body(blockIdx.x, threadIdx.x, outt, Wf1, bf1, partB, gf1, btf1, Wf2, bf2,
            Yf2, partA, scshL, otT, fT, s1, s2);
}

__global__ void k_ffn2M(const float* __restrict__ outt0, const float* __restrict__ outt1,
                        const float* __restrict__ Wf1b, const float* __restrict__ bf1b,
                        const float* __restrict__ partB0, const float* __restrict__ partB1,
                        const float* __restrict__ gf1b, const float* __restrict__ btf1b,
                        const float* __restrict__ Wf2b, const float* __restrict__ bf2b,
                        float* __restrict__ Yf2_0, float* __restrict__ Yf2_1,
                        float* __restrict__ partA0, float* __restrict__ partA1){
  __shared__ float scshL[512];
  __shared__ float otT[64*36];
  __shared__ float fT[256*36];
  __shared__ float s1[1024], s2[1024];
  int t  = blockIdx.x >> 8;
  int bx = blockIdx.x & 255;
  ffn2_body(bx, threadIdx.x, t ? outt1 : outt0, Wf1b + t*CCH*C4, bf1b + t*C4,
            t ? partB1 : partB0, gf1b + t*C4, btf1b + t*C4,
            Wf2b + t*C4*CCH, bf2b + t*64, t ? Yf2_1 : Yf2_0,
            t ? partA1 : partA0, scshL, otT, fT, s1, s2);
}

// ---------------- final body ----------------
__device__ __forceinline__ void final_body(int bx, int tid,
    const float* __restrict__ Yf2, const float* __restrict__ partA,
    const float* __restrict__ gf2, const float* __restrict__ btf2,
    const float* __restrict__ outt, float* __restrict__ feat,
    float* scshL, float* s1, float* s2){
  {
    int c = tid & 63, sl = tid >> 6;
    float sm=0.f, ss=0.f;
    #pragma unroll 4
    for (int u=sl*64; u<sl*64+64; u++){ sm += partA[u*128+c]; ss += partA[u*128+64+c]; }
    s1[tid]=sm; s2[tid]=ss;
  }
  __syncthreads();
  if (tid < 64){
    float sm = s1[tid]+s1[64+tid]+s1[128+tid]+s1[192+tid];
    float ss = s2[tid]+s2[64+tid]+s2[128+tid]+s2[192+tid];
    float mean = sm/(float)R1;
    float var = fmaxf(ss/(float)R1 - mean*mean, 0.f);
    float sc = gf2[tid]*rsqrtf(var+1e-5f);
    scshL[tid] = sc; scshL[64+tid] = btf2[tid] - mean*sc;
  }
  __syncthreads();
  size_t base = (size_t)bx*2048;
  for (int p=0; p<8; p++){
    size_t idx = base + p*256 + tid;
    int cc = idx & 63;
    feat[idx] = fmaf(Yf2[idx], scshL[cc], scshL[64+cc]) + outt[idx];
  }
}

__global__ void k_final(const float* __restrict__ Yf2, const float* __restrict__ partA,
                        const float* __restrict__ gf2, const float* __restrict__ btf2,
                        const float* __restrict__ outt, float* __restrict__ feat){
  __shared__ float scshL[128];
  __shared__ float s1[256], s2[256];
  final_body(blockIdx.x, threadIdx.x, Yf2, partA, gf2, btf2, outt, feat, scshL, s1, s2);
}

__global__ void k_finalM(const float* __restrict__ Yf2_0, const float* __restrict__ Yf2_1,
                         const float* __restrict__ partA0, const float* __restrict__ partA1,
                         const float* __restrict__ gf2b, const float* __restrict__ btf2b,
                         const float* __restrict__ outt0, const float* __restrict__ outt1,
                         float* __restrict__ f0, float* __restrict__ f1){
  __shared__ float scshL[128];
  __shared__ float s1[256], s2[256];
  int t  = blockIdx.x >> 8;
  int bx = blockIdx.x & 255;
  final_body(bx, threadIdx.x, t ? Yf2_1 : Yf2_0, t ? partA1 : partA0,
             gf2b + t*64, btf2b + t*64, t ? outt1 : outt0,
             t ? f1 : f0, scshL, s1, s2);
}

// ----- finalmix: BNf2+residual for BOTH t, alpha-mix, transposed write -> out -----
__global__ void k_finalmix(const float* __restrict__ Yf2_0, const float* __restrict__ Yf2_1,
                           const float* __restrict__ partA0, const float* __restrict__ partA1,
                           const float* __restrict__ gf2b, const float* __restrict__ btf2b,
                           const float* __restrict__ outt0, const float* __restrict__ outt1,
                           const float* __restrict__ alpha, float* __restrict__ outv){
  __shared__ float scsh0[128], scsh1[128];
  __shared__ float s1[256], s2[256];
  __shared__ float tile0[64*33], tile1[64*33];
  int tid = threadIdx.x, bx = blockIdx.x;
  {
    int c = tid & 63, sl = tid >> 6;
    float sm=0.f, ss=0.f;
    #pragma unroll 4
    for (int u=sl*64; u<sl*64+64; u++){ sm += partA0[u*128+c]; ss += partA0[u*128+64+c]; }
    s1[tid]=sm; s2[tid]=ss;
  }
  __syncthreads();
  if (tid < 64){
    float sm = s1[tid]+s1[64+tid]+s1[128+tid]+s1[192+tid];
    float ss = s2[tid]+s2[64+tid]+s2[128+tid]+s2[192+tid];
    float mean = sm/(float)R1;
    float var = fmaxf(ss/(float)R1 - mean*mean, 0.f);
    float sc = gf2b[tid]*rsqrtf(var+1e-5f);
    scsh0[tid] = sc; scsh0[64+tid] = btf2b[tid] - mean*sc;
  }
  __syncthreads();
  {
    int c = tid & 63, sl = tid >> 6;
    float sm=0.f, ss=0.f;
    #pragma unroll 4
    for (int u=sl*64; u<sl*64+64; u++){ sm += partA1[u*128+c]; ss += partA1[u*128+64+c]; }
    s1[tid]=sm; s2[tid]=ss;
  }
  __syncthreads();
  if (tid < 64){
    float sm = s1[tid]+s1[64+tid]+s1[128+tid]+s1[192+tid];
    float ss = s2[tid]+s2[64+tid]+s2[128+tid]+s2[192+tid];
    float mean = sm/(float)R1;
    float var = fmaxf(ss/(float)R1 - mean*mean, 0.f);
    float sc = gf2b[64+tid]*rsqrtf(var+1e-5f);
    scsh1[tid] = sc; scsh1[64+tid] = btf2b[64+tid] - mean*sc;
  }
  __syncthreads();
  size_t base = (size_t)bx*2048;
  #pragma unroll
  for (int p=0; p<8; p++){
    size_t idx = base + p*256 + tid;
    int cc = idx & 63;
    int nl = (int)((idx >> 6) & 31);
    float f0v = fmaf(Yf2_0[idx], scsh0[cc], scsh0[64+cc]) + outt0[idx];
    float f1v = fmaf(Yf2_1[idx], scsh1[cc], scsh1[64+cc]) + outt1[idx];
    tile0[cc*33 + nl] = f0v;
    tile1[cc*33 + nl] = f1v;
  }
  __syncthreads();
  int b  = bx >> 7;
  int n0 = (bx & 127) * 32;
  float a00 = alpha[0], a01 = alpha[1];
  float a10 = alpha[TT], a11 = alpha[TT+1];
  #pragma unroll
  for (int q=0; q<2; q++){
    int slot = tid + q*256;
    int c  = slot >> 3;
    int f4 = slot & 7;
    float v0[4], v1[4];
    #pragma unroll
    for (int k2=0;k2<4;k2++){
      v0[k2] = tile0[c*33 + f4*4 + k2];
      v1[k2] = tile1[c*33 + f4*4 + k2];
    }
    size_t o0 = ((size_t)((0*BB + b)*CCH + c))*NN + n0 + f4*4;
    size_t o1 = ((size_t)((1*BB + b)*CCH + c))*NN + n0 + f4*4;
    *(float4*)&outv[o0] = make_float4(a00*v0[0] + a01*v1[0], a00*v0[1] + a01*v1[1],
                                      a00*v0[2] + a01*v1[2], a00*v0[3] + a01*v1[3]);
    *(float4*)&outv[o1] = make_float4(a10*v0[0] + a11*v1[0], a10*v0[1] + a11*v1[1],
                                      a10*v0[2] + a11*v1[2], a10*v0[3] + a11*v1[3]);
  }
}

// ---------------- alpha-mix + transpose -> output (T,B,C,N) fp32 ----------------
__global__ void k_mix(const float* __restrict__ f0, const float* __restrict__ f1,
                      const float* __restrict__ alpha, float* __restrict__ outv){
  int idx = blockIdx.x*256 + threadIdx.x;
  if (idx >= TT*BB*CCH*NN) return;
  int n = idx & (NN-1);
  int c = (idx >> 12) & 63;
  int b = (idx >> 18) & 1;
  int i = idx >> 19;
  float a0 = alpha[i*TT + 0];
  float a1 = alpha[i*TT + 1];
  size_t fi = ((size_t)(b*NN + n))*64 + c;
  outv[idx] = a0*f0[fi] + a1*f1[fi];
}

extern "C" void kernel_launch(void* const* d_in, const int* in_sizes, int n_in,
                              void* d_out, int out_size, void* d_ws, size_t ws_size,
                              hipStream_t stream){
  float* outp = (float*)d_out;

  static const int expect[22] = {
    524288, 8192, 128, 128, 128, 32768, 256, 256, 256, 16384, 128, 128, 128,
    32768, 512, 512, 512, 32768, 128, 128, 128, 4
  };
  bool ok = (n_in == 22) && (out_size == TT*BB*CCH*NN) &&
            (ws_size >= WS_TOTAL*sizeof(float));
  if (ok){
    for (int i=0;i<22;i++) if (in_sizes[i] != expect[i]) { ok = false; break; }
  }
  if (!ok){
    k_zero<<<(out_size+255)/256,256,0,stream>>>(outp, out_size);
    return;
  }
  const bool bigws   = (ws_size >= WS_BIG*sizeof(float));
  const bool merged  = (ws_size >= WS_M1*sizeof(float));
  const bool merged2 = (ws_size >= WS_M2*sizeof(float));
  const bool merged3 = (ws_size >= WS_M3*sizeof(float));

  const float* x   = (const float*)d_in[0];
  const float* W1  = (const float*)d_in[1];
  const float* b1  = (const float*)d_in[2];
  const float* g1  = (const float*)d_in[3];
  const float* bt1 = (const float*)d_in[4];
  const float* Wg  = (const float*)d_in[5];
  const float* bg  = (const float*)d_in[6];
  const float* gg  = (const float*)d_in[7];
  const float* btg = (const float*)d_in[8];
  const float* W2  = (const float*)d_in[9];
  const float* b2v = (const float*)d_in[10];
  const float* g2  = (const float*)d_in[11];
  const float* bt2 = (const float*)d_in[12];
  const float* Wf1 = (const float*)d_in[13];
  const float* bf1v= (const float*)d_in[14];
  const float* gf1 = (const float*)d_in[15];
  const float* btf1= (const float*)d_in[16];
  const float* Wf2 = (const float*)d_in[17];
  const float* bf2v= (const float*)d_in[18];
  const float* gf2 = (const float*)d_in[19];
  const float* btf2= (const float*)d_in[20];
  const float* alpha=(const float*)d_in[21];
  float* ws = (float*)d_ws;

  float* x0f  = ws + 0;
  float* hbuf = ws + 524288;
  float* xnb  = ws + 1048576;
  float* sqb  = ws + 1572864;
  float* partA= ws + 1581056;
  int*   idxf = (int*)(ws + 1712640);
  float* f0   = ws + 1786368;
  float* f1b  = ws + 2310656;
  float* Rbig = ws + 2834944;
  float* pdist = Rbig;
  int*   pidx  = (int*)(Rbig + (size_t)R1*SPLIT*9);
  float* gmaxb = Rbig;
  float* outt  = Rbig + 1048576;
  float* Y2    = Rbig + 1572864;
  float* partB = Rbig + 2097152;
  float* Yf2   = Rbig;
  float* Yg    = ws + WS_TOTAL;
  /* merged-front tier buffers */
  float* hbuf1  = ws + WS_BIG;
  float* xnb1   = hbuf1 + 524288;
  float* sqb1   = xnb1 + 524288;
  float* partA1 = sqb1 + 8192;
  float* pd1    = partA1 + 32768;
  int*   pi1    = (int*)(pd1 + (size_t)R1*SPLIT*9);
  /* merged-back tier buffers */
  float* gmax1  = ws + WS_M1;
  float* Y2_1   = gmax1 + 1048576;
  float* outt1  = Y2_1 + 524288;
  float* partB1 = outt1 + 524288;
  float* Yf2_1  = partB1 + 131072;
  /* merged-edge tier buffers */
  float* Yg1    = ws + WS_M2;
  int*   idxf1  = (int*)(Yg1 + 9437184);
  float* partE1 = (float*)(idxf1 + 73728);

  /* merged3 fuses the transpose into gemm1MT; all other tiers need x0f first */
  if (!merged3){
    k_transpose<<<2048,256,0,stream>>>(x, x0f);
  }
  float* feats[2] = {f0, f1b};
  bool did_mix = false;

  if (merged){
    if (merged3){
      k_gemm1MT<<<512,256,0,stream>>>(x, W1, b1, hbuf, hbuf1, partA, partA1, x0f);
    } else {
      k_gemm1M<<<512,256,0,stream>>>(x0f, W1, b1, hbuf, hbuf1, partA, partA1);
    }
    k_applynormM<<<512,256,0,stream>>>(hbuf, hbuf1, partA, partA1, g1, bt1,
                                       xnb, xnb1, sqb, sqb1);
    /* knn split: two launches overlap tail/head naturally; in-kernel t-loop
       (k_knn2, r17) serialized phases and cost ~6us. */
    k_knn<<<256,512,0,stream>>>(xnb, sqb, pdist, pidx);
    k_knn<<<256,512,0,stream>>>(xnb1, sqb1, pd1, pi1);
    if (merged3){
      k_edge1M<<<1024,256,0,stream>>>(hbuf, hbuf1, pdist, pd1, pidx, pi1,
                                      Wg, bg, idxf, idxf1, partA, partE1,
                                      Yg, Yg1);
      k_edge2mM<<<1024,256,0,stream>>>(Yg, Yg1, partA, partE1, gg, btg,
                                       gmaxb, gmax1);
      k_gemm2M<<<512,256,0,stream>>>(gmaxb, gmax1, W2, b2v, Y2, Y2_1, partA, partA1);
      k_ffn1M<<<512,256,0,stream>>>(Y2, Y2_1, partA, partA1, g2, bt2, x0f,
                                    outt, outt1, Wf1, bf1v, partB, partB1);
      k_ffn2M<<<512,256,0,stream>>>(outt, outt1, Wf1, bf1v, partB, partB1,
                                    gf1, btf1, Wf2, bf2v, Yf2, Yf2_1, partA, partA1);
      k_finalmix<<<256,256,0,stream>>>(Yf2, Yf2_1, partA, partA1, gf2, btf2,
                                       outt, outt1, alpha, outp);
      did_mix = true;
    } else if (merged2){
      k_edge1<<<512,256,0,stream>>>(hbuf, pdist, pidx, Wg, bg, idxf, partA, Yg, 1);
      k_edge2m<<<512,256,0,stream>>>(Yg, partA, gg, btg, gmaxb);
      k_edge1<<<512,256,0,stream>>>(hbuf1, pd1, pi1, Wg + C2*C2, bg + C2, idxf, partA, Yg, 1);
      k_edge2m<<<512,256,0,stream>>>(Yg, partA, gg + C2, btg + C2, gmax1);
      k_gemm2M<<<512,256,0,stream>>>(gmaxb, gmax1, W2, b2v, Y2, Y2_1, partA, partA1);
      k_ffn1M<<<512,256,0,stream>>>(Y2, Y2_1, partA, partA1, g2, bt2, x0f,
                                    outt, outt1, Wf1, bf1v, partB, partB1);
      k_ffn2M<<<512,256,0,stream>>>(outt, outt1, Wf1, bf1v, partB, partB1,
                                    gf1, btf1, Wf2, bf2v, Yf2, Yf2_1, partA, partA1);
      k_finalM<<<512,256,0,stream>>>(Yf2, Yf2_1, partA, partA1, gf2, btf2,
                                     outt, outt1, f0, f1b);
    } else {
      for (int t=0; t<TT; t++){
        float* h_t  = t ? hbuf1 : hbuf;
        float* pd_t = t ? pd1 : pdist;
        int*   pi_t = t ? pi1 : pidx;
        k_edge1<<<512,256,0,stream>>>(h_t, pd_t, pi_t, Wg + t*C2*C2, bg + t*C2,
                                      idxf, partA, Yg, 1);
        k_edge2m<<<512,256,0,stream>>>(Yg, partA, gg + t*C2, btg + t*C2, gmaxb);
        k_gemm2_stats<<<256,256,0,stream>>>(gmaxb, W2 + t*C2*CCH, b2v + t*64, Y2, partA);
        k_ffn1_fused<<<256,256,0,stream>>>(Y2, partA, g2 + t*64, bt2 + t*64, x0f, outt,
                                           Wf1 + t*CCH*C4, bf1v + t*C4, partB);
        k_ffn2_fused<<<256,256,0,stream>>>(outt, Wf1 + t*CCH*C4, bf1v + t*C4, partB,
                                           gf1 + t*C4, btf1 + t*C4,
                                           Wf2 + t*C4*CCH, bf2v + t*64, Yf2, partA);
        k_final<<<256,256,0,stream>>>(Yf2, partA, gf2 + t*64, btf2 + t*64, outt, feats[t]);
      }
    }
  } else {
    for (int t=0; t<TT; t++){
      k_gemm1_stats<<<256,256,0,stream>>>(x0f, W1 + t*CCH*CCH, b1 + t*64, hbuf, partA);
      k_applynorm3<<<256,256,0,stream>>>(hbuf, partA, g1 + t*64, bt1 + t*64, xnb, sqb);
      k_knn<<<256,512,0,stream>>>(xnb, sqb, pdist, pidx);
      k_edge1<<<512,256,0,stream>>>(hbuf, pdist, pidx, Wg + t*C2*C2, bg + t*C2, idxf, partA,
                                    bigws ? Yg : hbuf, bigws ? 1 : 0);
      if (bigws){
        k_edge2m<<<512,256,0,stream>>>(Yg, partA, gg + t*C2, btg + t*C2, gmaxb);
      } else {
        k_edge2<<<512,256,0,stream>>>(hbuf, idxf, Wg + t*C2*C2, bg + t*C2,
                                      partA, gg + t*C2, btg + t*C2, gmaxb);
      }
      k_gemm2_stats<<<256,256,0,stream>>>(gmaxb, W2 + t*C2*CCH, b2v + t*64, Y2, partA);
      k_ffn1_fused<<<256,256,0,stream>>>(Y2, partA, g2 + t*64, bt2 + t*64, x0f, outt,
                                         Wf1 + t*CCH*C4, bf1v + t*C4, partB);
      k_ffn2_fused<<<256,256,0,stream>>>(outt, Wf1 + t*CCH*C4, bf1v + t*C4, partB,
                                         gf1 + t*C4, btf1 + t*C4,
                                         Wf2 + t*C4*CCH, bf2v + t*64, Yf2, partA);
      k_final<<<256,256,0,stream>>>(Yf2, partA, gf2 + t*64, btf2 + t*64, outt, feats[t]);
    }
  }
  if (!did_mix){
    k_mix<<<4096,256,0,stream>>>(f0, f1b, alpha, outp);
  }
}